// Round 5
// baseline (2375.039 us; speedup 1.0000x reference)
//
#include <hip/hip_runtime.h>
#include <math.h>

#define DEV __device__ __forceinline__

using v8s = __attribute__((ext_vector_type(8))) short;   // 8 bf16 (4 VGPRs)
using v4f = __attribute__((ext_vector_type(4))) float;   // 4 fp32 acc

// ---------- bf16 helpers (RNE) ----------
DEV short f2bf(float f) {
    unsigned u = __float_as_uint(f);
    unsigned r = (u + 0x7fffu + ((u >> 16) & 1u)) >> 16;
    return (short)(unsigned short)r;
}
DEV float bf2f(short s) {
    return __uint_as_float(((unsigned)(unsigned short)s) << 16);
}

// async global->LDS, 16B per lane; dest = wave-uniform base + lane*16
DEV void gload16(const short* g, short* l) {
    __builtin_amdgcn_global_load_lds((const __attribute__((address_space(1))) void*)g,
                                     (__attribute__((address_space(3))) void*)l,
                                     16, 0, 0);
}

// ---------- block reductions (256 threads = 4 waves) ----------
DEV float block_sum256(float v, float* red) {
    __syncthreads();
#pragma unroll
    for (int o = 32; o >= 1; o >>= 1) v += __shfl_down(v, o, 64);
    if ((threadIdx.x & 63) == 0) red[threadIdx.x >> 6] = v;
    __syncthreads();
    return red[0] + red[1] + red[2] + red[3];
}
DEV float block_max256(float v, float* red) {
    __syncthreads();
#pragma unroll
    for (int o = 32; o >= 1; o >>= 1) v = fmaxf(v, __shfl_down(v, o, 64));
    if ((threadIdx.x & 63) == 0) red[threadIdx.x >> 6] = v;
    __syncthreads();
    return fmaxf(fmaxf(red[0], red[1]), fmaxf(red[2], red[3]));
}

// tiled element offset: panel(128 rows) * 128*K + (k/32)*4096 + ((k%32)/8)*1024 + row*8 + k%8
// group form (8 consecutive k = one ushort4 pair): g=k/8:
DEV long tile_goff(int row, int g) {   // within a panel, K arbitrary
    return ((long)(g >> 2) << 12) + ((long)(g & 3) << 10) + ((long)(row & 127) << 3);
}

// ---------------- model constants ----------------
// V=32000 D=1024 L=2 H=16 KVH=4 HD=64 E=8 FF=2048 K=2 B=2 S=1024

// ---------------- weight conversion to TILED layout ----------------
__global__ __launch_bounds__(256) void conv_tile(const float* __restrict__ src,
                                                 short* __restrict__ hi, short* __restrict__ lo,
                                                 long nGroups, int Kg, long chunkRows, long chunkPanelStride) {
    const long panelElems = 128L * Kg * 8;
    for (long idx = (long)blockIdx.x * 256 + threadIdx.x; idx < nGroups; idx += (long)gridDim.x * 256) {
        long rrow = idx / Kg; int g = (int)(idx - rrow * Kg);
        long c = rrow / chunkRows; int ri = (int)(rrow - c * chunkRows);
        long panel = c * chunkPanelStride + (ri >> 7);
        long dst = panel * panelElems + ((long)(g >> 2) << 12) + ((long)(g & 3) << 10) + ((long)(ri & 127) << 3);
        const float4 f0 = ((const float4*)src)[idx * 2];
        const float4 f1 = ((const float4*)src)[idx * 2 + 1];
        short h0 = f2bf(f0.x), h1 = f2bf(f0.y), h2 = f2bf(f0.z), h3 = f2bf(f0.w);
        short h4 = f2bf(f1.x), h5 = f2bf(f1.y), h6 = f2bf(f1.z), h7 = f2bf(f1.w);
        *(ushort4*)(hi + dst)     = make_ushort4((unsigned short)h0, (unsigned short)h1,
                                                 (unsigned short)h2, (unsigned short)h3);
        *(ushort4*)(hi + dst + 4) = make_ushort4((unsigned short)h4, (unsigned short)h5,
                                                 (unsigned short)h6, (unsigned short)h7);
        if (lo) {
            short l0 = f2bf(f0.x - bf2f(h0)), l1 = f2bf(f0.y - bf2f(h1));
            short l2 = f2bf(f0.z - bf2f(h2)), l3 = f2bf(f0.w - bf2f(h3));
            short l4 = f2bf(f1.x - bf2f(h4)), l5 = f2bf(f1.y - bf2f(h5));
            short l6 = f2bf(f1.z - bf2f(h6)), l7 = f2bf(f1.w - bf2f(h7));
            *(ushort4*)(lo + dst)     = make_ushort4((unsigned short)l0, (unsigned short)l1,
                                                     (unsigned short)l2, (unsigned short)l3);
            *(ushort4*)(lo + dst + 4) = make_ushort4((unsigned short)l4, (unsigned short)l5,
                                                     (unsigned short)l6, (unsigned short)l7);
        }
    }
}

// ---------------- generic GEMM ----------------
// C[M,N] = A[M,K] * B[N,K]^T, bf16 hi(+lo) planes, fp32 accum.
// A: tiled (gload) unless AREG (row-major reg-staged, for PV). B: always tiled (gload).
struct GemmP {
    const short* Ah; const short* Al;
    const short* Bh; const short* Bl;
    float* C; short* Ch; short* Cl;
    const int* cnt; const int* ppd; const int* lrow;
    long aPanelsZ;            // A panels per z (tiled, non-grouped)
    long strideAz;            // AREG: A elems per z
    long strideBz, strideCz;
    int M, N, K, lda, ldc;
    float alpha;
    int outMode;    // 0 store f32, 1 C += alpha*acc, 3 split-bf16 TILED attn store (Ch/Cl)
    int gqaB;       // B z-offset uses GQA mapping (z=b*16+h -> b*4+h/4)
    int grouped;    // 0 none; 1: A panels at ppd[z]>>7, C row = ppd[z]+m; 2: A same, C row = lrow[z*2048+m]
    int causalSkip; // skip blocks with nt > mt
    int causalK;    // limit K loop to (mt+1)*128
    int ntiles, S, G; // group decode: group=(nt,z), member=mt; S=mtiles, G=ntiles*zdim
};

template<bool SPLIT, bool AREG>
__global__ __launch_bounds__(256) void gemm_bt(GemmP p) {
    // ---- XCD-group decode: all members (mt) of one B-panel group on one XCD ----
    const int lid = blockIdx.x;
    const int xcd = lid & 7, sI = lid >> 3;
    const int gi = xcd + 8 * (sI / p.S);
    if (gi >= p.G) return;
    const int mt = sI % p.S;
    const int nt = gi % p.ntiles;
    const int z  = gi / p.ntiles;
    if (p.causalSkip && nt > mt) return;

    const int tid = threadIdx.x;

    int Mz = p.grouped ? p.cnt[z] : p.M;
    if (mt * 128 >= Mz) return;

    long bOff;
    if (p.gqaB) { int b = z >> 4, h = z & 15; bOff = (long)(b * 4 + (h >> 2)) * p.strideBz; }
    else bOff = (long)z * p.strideBz;

    extern __shared__ char smem[];
    short* Ahs = (short*)smem;          // [4][128][8]
    short* Bhs = Ahs + 4096;
    short* Als = Bhs + 4096;            // SPLIT only
    short* Bls = Als + 4096;

    const int lane = tid & 63, w = tid >> 6;
    const int lr = lane & 15, lg = lane >> 4;
    const int wr = w >> 1, wc = w & 1;

    v4f acc[4][4];
#pragma unroll
    for (int i = 0; i < 4; ++i)
#pragma unroll
        for (int j = 0; j < 4; ++j) { acc[i][j][0] = 0.f; acc[i][j][1] = 0.f; acc[i][j][2] = 0.f; acc[i][j][3] = 0.f; }

    // ---- B gload pointers (tiled): wave w stages kg=w ----
    const short* bks  = p.Bh + bOff + (long)nt * 128 * p.K + (long)w * 1024 + lane * 8;
    const short* bksL = SPLIT ? p.Bl + bOff + (long)nt * 128 * p.K + (long)w * 1024 + lane * 8 : nullptr;
    short* dB  = Bhs + w * 1024;
    short* dBl = Bls + w * 1024;

    // ---- A pointers ----
    const short *aks = nullptr, *aksL = nullptr;     // tiled path
    short *dA = nullptr, *dAl = nullptr;
    const short *aH = nullptr, *aL = nullptr;        // AREG path
    short *sA0 = nullptr, *sA1 = nullptr, *sA0l = nullptr, *sA1l = nullptr;
    if constexpr (AREG) {
        const int r = tid & 127;
        const int kgA = tid >> 7;
        int am = mt * 128 + r; if (am >= Mz) am = Mz - 1;
        long arowoff = (long)z * p.strideAz + (long)am * p.lda;
        aH = p.Ah + arowoff + kgA * 16;
        aL = SPLIT ? p.Al + arowoff + kgA * 16 : nullptr;
        sA0 = Ahs + (kgA * 256 + r) * 8; sA1 = sA0 + 1024;
        sA0l = Als + (kgA * 256 + r) * 8; sA1l = sA0l + 1024;
    } else {
        long aPanel = (p.grouped ? (long)(p.ppd[z] >> 7) : (long)z * p.aPanelsZ) + mt;
        aks  = p.Ah + aPanel * 128L * p.K + (long)w * 1024 + lane * 8;
        aksL = SPLIT ? p.Al + aPanel * 128L * p.K + (long)w * 1024 + lane * 8 : nullptr;
        dA  = Ahs + w * 1024;
        dAl = Als + w * 1024;
    }

    const int kEnd = p.causalK ? min(p.K, (mt + 1) * 128) : p.K;

    for (int k0 = 0; k0 < kEnd; k0 += 32) {
        const long kb = (long)k0 * 128;       // tiled elems per kblk = 4096
        uint4 a0, a1, a0l, a1l;
        if constexpr (AREG) {
            a0 = *(const uint4*)(aH + k0);
            a1 = *(const uint4*)(aH + k0 + 8);
            if (SPLIT) { a0l = *(const uint4*)(aL + k0); a1l = *(const uint4*)(aL + k0 + 8); }
        }
        __syncthreads();
        gload16(bks + kb,       dB);
        gload16(bks + kb + 512, dB + 512);
        if (SPLIT) {
            gload16(bksL + kb,       dBl);
            gload16(bksL + kb + 512, dBl + 512);
        }
        if constexpr (AREG) {
            *(uint4*)sA0 = a0; *(uint4*)sA1 = a1;
            if (SPLIT) { *(uint4*)sA0l = a0l; *(uint4*)sA1l = a1l; }
        } else {
            gload16(aks + kb,       dA);
            gload16(aks + kb + 512, dA + 512);
            if (SPLIT) {
                gload16(aksL + kb,       dAl);
                gload16(aksL + kb + 512, dAl + 512);
            }
        }
        __syncthreads();
        const int abase = lg * 1024 + (wr * 64 + lr) * 8;
        const int bbase = lg * 1024 + (wc * 64 + lr) * 8;
        v8s ah[4], bh[4];
#pragma unroll
        for (int i = 0; i < 4; ++i) {
            ah[i] = *(const v8s*)(Ahs + abase + i * 128);
            bh[i] = *(const v8s*)(Bhs + bbase + i * 128);
        }
        if constexpr (SPLIT) {
            v8s al[4], bl[4];
#pragma unroll
            for (int i = 0; i < 4; ++i) {
                al[i] = *(const v8s*)(Als + abase + i * 128);
                bl[i] = *(const v8s*)(Bls + bbase + i * 128);
            }
#pragma unroll
            for (int mi = 0; mi < 4; ++mi)
#pragma unroll
                for (int nj = 0; nj < 4; ++nj) {
                    acc[mi][nj] = __builtin_amdgcn_mfma_f32_16x16x32_bf16(ah[mi], bh[nj], acc[mi][nj], 0, 0, 0);
                    acc[mi][nj] = __builtin_amdgcn_mfma_f32_16x16x32_bf16(al[mi], bh[nj], acc[mi][nj], 0, 0, 0);
                    acc[mi][nj] = __builtin_amdgcn_mfma_f32_16x16x32_bf16(ah[mi], bl[nj], acc[mi][nj], 0, 0, 0);
                }
        } else {
#pragma unroll
            for (int mi = 0; mi < 4; ++mi)
#pragma unroll
                for (int nj = 0; nj < 4; ++nj)
                    acc[mi][nj] = __builtin_amdgcn_mfma_f32_16x16x32_bf16(ah[mi], bh[nj], acc[mi][nj], 0, 0, 0);
        }
    }

    // ---- epilogue: D[row=(lane>>4)*4+r][col=lane&15] ----
#pragma unroll
    for (int mi = 0; mi < 4; ++mi) {
        const int mrow = mt * 128 + wr * 64 + mi * 16 + lg * 4;
#pragma unroll
        for (int nj = 0; nj < 4; ++nj) {
            const int ncol = nt * 128 + wc * 64 + nj * 16 + lr;
            if (ncol < p.N) {
#pragma unroll
                for (int rr = 0; rr < 4; ++rr) {
                    const int m = mrow + rr;
                    if (m < Mz) {
                        float v = acc[mi][nj][rr] * p.alpha;
                        if (p.outMode == 3) {
                            // tiled split attn-out store: z=b*16+h
                            int b = z >> 4, h = z & 15;
                            int grow = b * 1024 + m, col = h * 64 + ncol;
                            long dst = ((long)(grow >> 7)) * 131072 + ((long)(col >> 5) << 12)
                                     + ((long)((col >> 3) & 3) << 10) + ((long)(grow & 127) << 3) + (col & 7);
                            short hi = f2bf(v);
                            p.Ch[dst] = hi;
                            p.Cl[dst] = f2bf(v - bf2f(hi));
                        } else {
                            long crow;
                            if (p.grouped == 1)      crow = p.ppd[z] + m;
                            else if (p.grouped == 2) crow = p.lrow[z * 2048 + m];
                            else                     crow = m;
                            long co = (long)z * p.strideCz + crow * (long)p.ldc + ncol;
                            if (p.outMode == 0) p.C[co] = v;
                            else                p.C[co] += v;
                        }
                    }
                }
            }
        }
    }
}

// ---------------- small kernels ----------------
__global__ __launch_bounds__(256) void embed_kernel(const int* toks, const float* emb, float* X) {
    const int t = blockIdx.x;
    const int tok = toks[t];
    const float4* s = (const float4*)(emb + (size_t)tok * 1024);
    float4* d = (float4*)(X + (size_t)t * 1024);
    d[threadIdx.x] = s[threadIdx.x];
}

// rmsnorm -> TILED split output (K=1024, panels of 128 rows)
__global__ __launch_bounds__(256) void rmsnorm_split(const float* X, const float* w, short* oh, short* ol) {
    __shared__ float red[4];
    const long t = blockIdx.x;
    const float* r = X + t * 1024;
    float ss = 0.f;
    for (int j = threadIdx.x; j < 1024; j += 256) { float f = r[j]; ss += f * f; }
    ss = block_sum256(ss, red);
    const float sc = 32.f / fmaxf(sqrtf(ss), 1e-6f);
    if (threadIdx.x < 128) {
        const int g = threadIdx.x, f = g * 8;
        float v[8];
#pragma unroll
        for (int j = 0; j < 8; ++j) v[j] = r[f + j] * sc * w[f + j];
        long dst = (t >> 7) * 131072 + ((long)(g >> 2) << 12) + ((long)(g & 3) << 10) + ((t & 127) << 3);
        short h[8], lo[8];
#pragma unroll
        for (int j = 0; j < 8; ++j) { h[j] = f2bf(v[j]); lo[j] = f2bf(v[j] - bf2f(h[j])); }
        *(ushort4*)(oh + dst)     = make_ushort4((unsigned short)h[0], (unsigned short)h[1], (unsigned short)h[2], (unsigned short)h[3]);
        *(ushort4*)(oh + dst + 4) = make_ushort4((unsigned short)h[4], (unsigned short)h[5], (unsigned short)h[6], (unsigned short)h[7]);
        *(ushort4*)(ol + dst)     = make_ushort4((unsigned short)lo[0], (unsigned short)lo[1], (unsigned short)lo[2], (unsigned short)lo[3]);
        *(ushort4*)(ol + dst + 4) = make_ushort4((unsigned short)lo[4], (unsigned short)lo[5], (unsigned short)lo[6], (unsigned short)lo[7]);
    }
}

struct RopeF { float f[32]; };

// Q-hat -> TILED per z (8 panels, K=64)
__global__ __launch_bounds__(256) void rope_q_kernel(const float* QKV, short* OH, short* OL, RopeF rf) {
    const int idx = blockIdx.x * 256 + threadIdx.x;           // B*S*H*32
    const int pp = idx & 31, h = (idx >> 5) & 15, s = (idx >> 9) & 1023, b = idx >> 19;
    const float* src = QKV + ((size_t)(b * 1024 + s)) * 1536 + h * 64 + 2 * pp;
    const float x0 = src[0], x1 = src[1];
    const float ang = (float)s * rf.f[pp];
    float sn, cs; sincosf(ang, &sn, &cs);
    const float o0 = x0 * cs - x1 * sn, o1 = x0 * sn + x1 * cs;
    const int z = b * 16 + h, d = 2 * pp;
    const long off = (long)z * 65536 + (long)(s >> 7) * 8192
                   + ((long)(d >> 5) << 12) + ((long)((d >> 3) & 3) << 10)
                   + ((long)(s & 127) << 3) + (d & 7);
    short h0 = f2bf(o0); OH[off] = h0; OL[off] = f2bf(o0 - bf2f(h0));
    short h1 = f2bf(o1); OH[off + 1] = h1; OL[off + 1] = f2bf(o1 - bf2f(h1));
}

// K-hat -> TILED per z=b*4+kv (8 panels, K=64)
__global__ __launch_bounds__(256) void rope_k_kernel(const float* QKV, short* KH, short* KL, RopeF rf) {
    const int idx = blockIdx.x * 256 + threadIdx.x;           // B*S*KVH*32
    const int pp = idx & 31, kv = (idx >> 5) & 3, s = (idx >> 7) & 1023, b = idx >> 17;
    const float* src = QKV + ((size_t)(b * 1024 + s)) * 1536 + 1024 + kv * 64 + 2 * pp;
    const float x0 = src[0], x1 = src[1];
    const float ang = (float)s * rf.f[pp];
    float sn, cs; sincosf(ang, &sn, &cs);
    const float o0 = x0 * cs - x1 * sn, o1 = x0 * sn + x1 * cs;
    const int z = b * 4 + kv, d = 2 * pp;
    const long off = (long)z * 65536 + (long)(s >> 7) * 8192
                   + ((long)(d >> 5) << 12) + ((long)((d >> 3) & 3) << 10)
                   + ((long)(s & 127) << 3) + (d & 7);
    short h0 = f2bf(o0); KH[off] = h0; KL[off] = f2bf(o0 - bf2f(h0));
    short h1 = f2bf(o1); KH[off + 1] = h1; KL[off + 1] = f2bf(o1 - bf2f(h1));
}

// V^T -> TILED per z: one padded 128-row panel, K=1024 (rows 64..127 zero)
__global__ __launch_bounds__(256) void transpose_v_kernel(const float* QKV, short* VH, short* VL) {
    const int idx = blockIdx.x * 256 + threadIdx.x;           // B*S*KVH*HD
    const int d = idx & 63, kv = (idx >> 6) & 3, s = (idx >> 8) & 1023, b = idx >> 18;
    const float f = QKV[((size_t)(b * 1024 + s)) * 1536 + 1280 + kv * 64 + d];
    const int z = b * 4 + kv;
    const long off = (long)z * 131072 + ((long)(s >> 5) << 12) + ((long)((s >> 3) & 3) << 10)
                   + ((long)d << 3) + (s & 7);
    short hi = f2bf(f);
    VH[off] = hi; VL[off] = f2bf(f - bf2f(hi));
    VH[off + 512] = 0; VL[off + 512] = 0;     // pad row d+64
}

// softmax in-place: row-major P hi|lo planes interleaved per row (lda 2048)
__global__ __launch_bounds__(256) void attn_softmax(float* SC) {
    const long row = blockIdx.x;                 // z*1024 + i
    const int i = (int)(row & 1023);
    float* r = SC + row * 1024;
    __shared__ float buf[1024];
    __shared__ float red[4];
    const int n = i + 1;
    for (int j = threadIdx.x; j < 1024; j += 256) buf[j] = r[j];
    __syncthreads();
    float m = -INFINITY;
    for (int j = threadIdx.x; j < n; j += 256) m = fmaxf(m, buf[j]);
    m = block_max256(m, red);
    float s = 0.f;
    for (int j = threadIdx.x; j < n; j += 256) { float e = expf(buf[j] - m); buf[j] = e; s += e; }
    s = block_sum256(s, red);
    const float inv = 1.f / s;
    short* rh = (short*)r;
    short* rl = rh + 1024;
    __syncthreads();
    for (int j = threadIdx.x; j < 1024; j += 256) {
        float pv = (j < n) ? buf[j] * inv : 0.f;
        short hi = f2bf(pv);
        rh[j] = hi;
        rl[j] = f2bf(pv - bf2f(hi));
    }
}

__global__ __launch_bounds__(256) void router_kernel(const float* X, const float* wn, const float* rw,
                                                     float* probs, float* lse, int* cnt, int* ltok, int* lrow) {
    __shared__ float xs[1024];
    __shared__ float red[4];
    __shared__ float lg[8];
    const int t = blockIdx.x;
    const float* r = X + (size_t)t * 1024;
    for (int j = threadIdx.x; j < 1024; j += 256) xs[j] = r[j];
    __syncthreads();
    float ss = 0.f;
    for (int j = threadIdx.x; j < 1024; j += 256) ss += xs[j] * xs[j];
    ss = block_sum256(ss, red);
    const float sc = 32.f / fmaxf(sqrtf(ss), 1e-6f);
    float acc[8] = {0, 0, 0, 0, 0, 0, 0, 0};
    for (int j = threadIdx.x; j < 1024; j += 256) {
        const float xv = xs[j] * wn[j];
#pragma unroll
        for (int e = 0; e < 8; ++e) acc[e] += xv * rw[e * 1024 + j];
    }
#pragma unroll
    for (int e = 0; e < 8; ++e) {
        float s = block_sum256(acc[e], red);
        if (threadIdx.x == 0) lg[e] = s * sc;
    }
    __syncthreads();
    if (threadIdx.x == 0) {
        float m = lg[0];
        for (int e = 1; e < 8; ++e) m = fmaxf(m, lg[e]);
        float ex[8], se = 0.f;
        for (int e = 0; e < 8; ++e) { ex[e] = expf(lg[e] - m); se += ex[e]; }
        const float inv = 1.f / se;
        float pr[8];
        for (int e = 0; e < 8; ++e) { pr[e] = ex[e] * inv; probs[(size_t)t * 8 + e] = pr[e]; }
        lse[t] = m + logf(se);
        int i1 = 0;
        for (int e = 1; e < 8; ++e) if (pr[e] > pr[i1]) i1 = e;
        int i2 = (i1 == 0) ? 1 : 0;
        for (int e = 0; e < 8; ++e) if (e != i1 && pr[e] > pr[i2]) i2 = e;
        int s1 = atomicAdd(&cnt[i1], 1); ltok[i1 * 2048 + s1] = t; lrow[i1 * 2048 + s1] = 2 * t;
        int s2 = atomicAdd(&cnt[i2], 1); ltok[i2 * 2048 + s2] = t; lrow[i2 * 2048 + s2] = 2 * t + 1;
    }
}

__global__ void prefix_kernel(const int* cnt, int* ppd) {
    if (threadIdx.x == 0 && blockIdx.x == 0) {
        int a = 0;
        for (int e = 0; e < 8; ++e) { ppd[e] = a; a += ((cnt[e] + 127) >> 7) << 7; }
    }
}

// gather XN (tiled) rows -> per-expert padded tiled GXN
__global__ __launch_bounds__(256) void gather_kernel(const short* XNH, const short* XNL,
                                                     const int* cnt, const int* ppd, const int* ltok,
                                                     short* GXNH, short* GXNL) {
    const int e = blockIdx.y, i = blockIdx.x;
    if (i >= cnt[e]) return;
    const int t = ltok[e * 2048 + i];
    const int pd = ppd[e] + i;
    const int plane = threadIdx.x >> 7, g = threadIdx.x & 127;
    const long goff = ((long)(g >> 2) << 12) + ((long)(g & 3) << 10);
    const long src = (long)(t >> 7) * 131072 + goff + ((t & 127) << 3);
    const long dst = (long)(pd >> 7) * 131072 + goff + ((pd & 127) << 3);
    const short* S = plane ? XNL : XNH;
    short* D = plane ? GXNL : GXNH;
    *(uint4*)(D + dst) = *(const uint4*)(S + src);
}

// silu(u)*g over padded U rows [5120][4096] -> tiled split H (K=2048)
__global__ __launch_bounds__(256) void silu_mul(const float* U, short* HH, short* HL) {
    const int row = blockIdx.x, g = threadIdx.x;   // 5120 blocks, 256 groups
    const float* ur = U + (long)row * 4096 + g * 8;
    const float4 u0 = *(const float4*)ur, u1 = *(const float4*)(ur + 4);
    const float4 g0 = *(const float4*)(ur + 2048), g1 = *(const float4*)(ur + 2052);
    float h[8];
    h[0] = (u0.x / (1.f + expf(-u0.x))) * g0.x;
    h[1] = (u0.y / (1.f + expf(-u0.y))) * g0.y;
    h[2] = (u0.z / (1.f + expf(-u0.z))) * g0.z;
    h[3] = (u0.w / (1.f + expf(-u0.w))) * g0.w;
    h[4] = (u1.x / (1.f + expf(-u1.x))) * g1.x;
    h[5] = (u1.y / (1.f + expf(-u1.y))) * g1.y;
    h[6] = (u1.z / (1.f + expf(-u1.z))) * g1.z;
    h[7] = (u1.w / (1.f + expf(-u1.w))) * g1.w;
    const long dst = (long)(row >> 7) * 262144 + ((long)(g >> 2) << 12) + ((long)(g & 3) << 10) + ((row & 127) << 3);
    short hh[8], ll[8];
#pragma unroll
    for (int j = 0; j < 8; ++j) { hh[j] = f2bf(h[j]); ll[j] = f2bf(h[j] - bf2f(hh[j])); }
    *(ushort4*)(HH + dst)     = make_ushort4((unsigned short)hh[0], (unsigned short)hh[1], (unsigned short)hh[2], (unsigned short)hh[3]);
    *(ushort4*)(HH + dst + 4) = make_ushort4((unsigned short)hh[4], (unsigned short)hh[5], (unsigned short)hh[6], (unsigned short)hh[7]);
    *(ushort4*)(HL + dst)     = make_ushort4((unsigned short)ll[0], (unsigned short)ll[1], (unsigned short)ll[2], (unsigned short)ll[3]);
    *(ushort4*)(HL + dst + 4) = make_ushort4((unsigned short)ll[4], (unsigned short)ll[5], (unsigned short)ll[6], (unsigned short)ll[7]);
}

__global__ __launch_bounds__(256) void combine_kernel(float* X, const float* Y) {
    const int i4 = blockIdx.x * 256 + threadIdx.x;            // 2048*1024/4
    const int t = i4 >> 8, d4 = i4 & 255;
    float4 x = ((float4*)X)[i4];
    const float4 a = ((const float4*)Y)[(size_t)(2 * t) * 256 + d4];
    const float4 b = ((const float4*)Y)[(size_t)(2 * t + 1) * 256 + d4];
    x.x += a.x + b.x; x.y += a.y + b.y; x.z += a.z + b.z; x.w += a.w + b.w;
    ((float4*)X)[i4] = x;
}

__global__ __launch_bounds__(256) void aux_kernel(const float* probs, const float* lse, float* auxb, int layer) {
    __shared__ float red[4];
    float sl = 0.f;
    for (int t = threadIdx.x; t < 2048; t += 256) sl += lse[t];
    sl = block_sum256(sl, red);
    float s1 = 0.f, s2 = 0.f;
    for (int i = threadIdx.x; i < 8192; i += 256) {
        const float l = probs[i] + probs[8192 + i];
        s1 += l; s2 += l * l;
    }
    s1 = block_sum256(s1, red);
    s2 = block_sum256(s2, red);
    if (threadIdx.x == 0) {
        const float ml = sl / 2048.f;
        const float mean = s1 / 8192.f;
        const float var = fmaxf((s2 - s1 * s1 / 8192.f) / 8191.f, 0.f);
        auxb[layer] = 0.001f * (ml * ml + var / (mean * mean));
    }
}

__global__ void finalize_aux(const float* auxb, float* out) {
    if (threadIdx.x == 0 && blockIdx.x == 0)
        out[(size_t)2 * 1024 * 32000] = auxb[0] + auxb[1];
}

// ---------------- launch helpers ----------------
static void run_gemm(hipStream_t s, bool split, bool areg, GemmP& p, int ntiles, int mtiles, int zdim) {
    p.ntiles = ntiles; p.S = mtiles;
    p.G = ntiles * zdim;
    int Gp = (p.G + 7) & ~7;
    long nb = (long)Gp * mtiles;
    dim3 g((unsigned)nb, 1, 1), b(256);
    if (split) {
        if (areg) gemm_bt<true, true><<<g, b, 32768, s>>>(p);
        else      gemm_bt<true, false><<<g, b, 32768, s>>>(p);
    } else {
        if (areg) gemm_bt<false, true><<<g, b, 16384, s>>>(p);
        else      gemm_bt<false, false><<<g, b, 16384, s>>>(p);
    }
}

static void run_tile(hipStream_t s, const float* src, short* hi, short* lo,
                     long rows, int K, long chunkRows, long chunkPanelStride) {
    long groups = rows * (K / 8);
    long nb = (groups + 255) / 256; if (nb > 2048) nb = 2048;
    conv_tile<<<(unsigned)nb, 256, 0, s>>>(src, hi, lo, groups, K / 8, chunkRows, chunkPanelStride);
}

extern "C" void kernel_launch(void* const* d_in, const int* in_sizes, int n_in,
                              void* d_out, int out_size, void* d_ws, size_t ws_size,
                              hipStream_t stream) {
    (void)in_sizes; (void)n_in; (void)out_size; (void)ws_size;
    const int*   tokens = (const int*)d_in[0];
    const float* tok_emb = (const float*)d_in[1];
    const float* norm1 = (const float*)d_in[2];
    const float* norm2 = (const float*)d_in[3];
    const float* wq = (const float*)d_in[4];
    const float* wk = (const float*)d_in[5];
    const float* wv = (const float*)d_in[6];
    const float* wo = (const float*)d_in[7];
    const float* rw = (const float*)d_in[8];
    const float* w1 = (const float*)d_in[9];
    const float* w2 = (const float*)d_in[10];
    const float* w3 = (const float*)d_in[11];
    const float* normf = (const float*)d_in[12];
    const float* headw = (const float*)d_in[13];
    float* out = (float*)d_out;

    char* w = (char*)d_ws;
    const size_t MB = 1024ull * 1024ull;
    float* X    = (float*)(w + 0);            // 8 MB residual fp32
    short* XNH  = (short*)(w + 8 * MB);       // tiled, 16 panels
    short* XNL  = (short*)(w + 12 * MB);
    short* QRH  = (short*)(w + 16 * MB);      // tiled Q-hat; aliased as AO tiled after QK^T
    short* QRL  = (short*)(w + 20 * MB);
    short* AOH  = QRH;
    short* AOL  = QRL;
    short* KRH  = (short*)(w + 24 * MB);      // 1 MB tiled
    short* KRL  = (short*)(w + 25 * MB);
    short* VTH  = (short*)(w + 26 * MB);      // 2 MB tiled padded
    short* VTL  = (short*)(w + 28 * MB);
    // BIG union region 32..168 MB:
    float* QKV  = (float*)(w + 32 * MB);      // 12 MB
    float* SC   = (float*)(w + 32 * MB);      // 128 MB scores / P planes in place
    float* U    = (float*)(w + 32 * MB);      // 80 MB padded [5120][4096]
    short* HH   = (short*)(w + 112 * MB);     // 20 MB tiled padded
    short* HL   = (short*)(w + 132 * MB);     // 20 MB
    float* Y    = (float*)(w + 152 * MB);     // 16 MB
    short* GXNH = (short*)(w + 168 * MB);     // 10 MB gathered tiled padded
    short* GXNL = (short*)(w + 178 * MB);     // 10 MB
    float* PROBS= (float*)(w + 188 * MB);               // 64 KB
    float* LSE  = (float*)(w + 188 * MB + 65536);       // 8 KB
    int*   CNT  = (int*)  (w + 188 * MB + 73728);
    int*   PPD  = (int*)  (w + 188 * MB + 73856);
    int*   LTOK = (int*)  (w + 188 * MB + 74240);       // 64 KB
    int*   LROW = (int*)  (w + 188 * MB + 74240 + 65536);
    float* AUXB = (float*)(w + 188 * MB + 74240 + 131072);
    // converted weights (all TILED):
    short* WQKVH = (short*)(w + 190 * MB);    // 6 MB
    short* WQKVL = (short*)(w + 196 * MB);    // 6 MB
    short* WOH   = (short*)(w + 202 * MB);    // 4 MB
    short* WOL   = (short*)(w + 206 * MB);    // 4 MB
    short* W12H  = (short*)(w + 210 * MB);    // 64 MB per-layer
    short* W12L  = (short*)(w + 274 * MB);    // 64 MB (layer 0 only; head aliases after)
    short* W3H   = (short*)(w + 338 * MB);    // 32 MB per-layer
    short* W3L   = (short*)(w + 370 * MB);    // 32 MB (layer 0 only)
    short* HDH   = (short*)(w + 274 * MB);    // 62.5 MB, aliases W12L (dead after l0 MoE)
    // total ~402 MB

    RopeF rf;
    for (int i = 0; i < 32; ++i) {
        float t = (float)pow(10000.0, (double)(2 * i) / 64.0);
        rf.f[i] = 1.0f / t;
    }

    // ---- weight conversion to tiled layout ----
    for (int l = 0; l < 2; ++l) {
        long qo = (long)l * 1572864;
        run_tile(stream, wq + (long)l * 1048576, WQKVH + qo,           WQKVL + qo,           1024, 1024, 1024, 8);
        run_tile(stream, wk + (long)l * 262144,  WQKVH + qo + 1048576, WQKVL + qo + 1048576, 256, 1024, 256, 2);
        run_tile(stream, wv + (long)l * 262144,  WQKVH + qo + 1310720, WQKVL + qo + 1310720, 256, 1024, 256, 2);
    }
    run_tile(stream, wo, WOH, WOL, 2048, 1024, 2048, 16);

    embed_kernel<<<2048, 256, 0, stream>>>(tokens, tok_emb, X);

    for (int l = 0; l < 2; ++l) {
        const bool msp = (l == 0);   // layer-0 MoE feeds layer-1 router -> split precision
        run_tile(stream, w1 + (long)l * 16777216, W12H,           msp ? W12L : nullptr,           16384, 1024, 2048, 32);
        run_tile(stream, w2 + (long)l * 16777216, W12H + 2097152, msp ? W12L + 2097152 : nullptr, 16384, 1024, 2048, 32);
        run_tile(stream, w3 + (long)l * 16777216, W3H,            msp ? W3L : nullptr,            8192, 2048, 8192, 64);

        rmsnorm_split<<<2048, 256, 0, stream>>>(X, norm1 + l * 1024, XNH, XNL);

        // fused QKV: [2048][1536] fp32
        { GemmP p = {}; p.Ah = XNH; p.Al = XNL; p.Bh = WQKVH + (long)l * 1572864; p.Bl = WQKVL + (long)l * 1572864;
          p.C = QKV; p.M = 2048; p.N = 1536; p.K = 1024; p.aPanelsZ = 16; p.ldc = 1536; p.alpha = 1.f;
          run_gemm(stream, true, false, p, 12, 16, 1); }

        rope_q_kernel<<<4096, 256, 0, stream>>>(QKV, QRH, QRL, rf);
        rope_k_kernel<<<1024, 256, 0, stream>>>(QKV, KRH, KRL, rf);
        transpose_v_kernel<<<2048, 256, 0, stream>>>(QKV, VTH, VTL);

        // scores = q k^T / 8  (causal tile skip), fp32 into SC
        { GemmP p = {}; p.Ah = QRH; p.Al = QRL; p.Bh = KRH; p.Bl = KRL; p.C = SC;
          p.M = 1024; p.N = 1024; p.K = 64; p.aPanelsZ = 8; p.ldc = 1024;
          p.strideBz = 65536; p.strideCz = 1048576;
          p.alpha = 0.125f; p.gqaB = 1; p.causalSkip = 1;
          run_gemm(stream, true, false, p, 8, 8, 32); }

        attn_softmax<<<32768, 256, 0, stream>>>(SC);

        // PV: A = P(hi|lo in-place, reg-staged), B = V^T tiled; out TILED split AO
        { GemmP p = {}; p.Ah = (short*)SC; p.Al = (short*)SC + 1024; p.Bh = VTH; p.Bl = VTL; p.Ch = AOH; p.Cl = AOL;
          p.M = 1024; p.N = 64; p.K = 1024; p.lda = 2048;
          p.strideAz = 2097152; p.strideBz = 131072;
          p.alpha = 1.f; p.gqaB = 1; p.causalK = 1; p.outMode = 3;
          run_gemm(stream, true, true, p, 1, 8, 32); }

        // x += 0.5 * attno @ wo^T
        { GemmP p = {}; p.Ah = AOH; p.Al = AOL; p.Bh = WOH + (long)l * 1048576; p.Bl = WOL + (long)l * 1048576; p.C = X;
          p.M = 2048; p.N = 1024; p.K = 1024; p.aPanelsZ = 16; p.ldc = 1024;
          p.alpha = 0.5f; p.outMode = 1;
          run_gemm(stream, true, false, p, 8, 16, 1); }

        // ---- MoE ----
        rmsnorm_split<<<2048, 256, 0, stream>>>(X, norm2 + l * 1024, XNH, XNL);
        hipMemsetAsync(CNT, 0, 8 * sizeof(int), stream);
        router_kernel<<<2048, 256, 0, stream>>>(X, norm2 + l * 1024, rw + (size_t)l * 8 * 1024,
                                                PROBS, LSE, CNT, LTOK, LROW);
        prefix_kernel<<<1, 64, 0, stream>>>(CNT, PPD);
        { dim3 gg(2048, 8); gather_kernel<<<gg, 256, 0, stream>>>(XNH, XNL, CNT, PPD, LTOK, GXNH, GXNL); }

        // fused u|g: C rows at padded positions
        { GemmP p = {}; p.Ah = GXNH; p.Al = GXNL; p.Bh = W12H; p.Bl = W12L; p.C = U;
          p.M = 2048; p.N = 4096; p.K = 1024; p.ldc = 4096;
          p.strideBz = 4194304; p.strideCz = 0; p.alpha = 1.f; p.grouped = 1;
          p.cnt = CNT; p.ppd = PPD; p.lrow = LROW;
          run_gemm(stream, msp, false, p, 32, 16, 8); }
        silu_mul<<<5120, 256, 0, stream>>>(U, HH, HL);
        // y = h @ w3^T, scatter rows by lrow into Y
        { GemmP p = {}; p.Ah = HH; p.Al = HL; p.Bh = W3H; p.Bl = W3L; p.C = Y;
          p.M = 2048; p.N = 1024; p.K = 2048; p.ldc = 1024;
          p.strideBz = 2097152; p.strideCz = 0; p.alpha = 1.f; p.grouped = 2;
          p.cnt = CNT; p.ppd = PPD; p.lrow = LROW;
          run_gemm(stream, msp, false, p, 8, 16, 8); }
        combine_kernel<<<2048, 256, 0, stream>>>(X, Y);
        aux_kernel<<<1, 256, 0, stream>>>(PROBS, LSE, AUXB, l);

        if (l == 0) // W12L/W3L dead now: convert head into aliased region
            run_tile(stream, headw, HDH, nullptr, 32000, 1024, 32000, 250);
    }

    rmsnorm_split<<<2048, 256, 0, stream>>>(X, normf, XNH, XNL);
    { GemmP p = {}; p.Ah = XNH; p.Bh = HDH; p.C = out;
      p.M = 2048; p.N = 32000; p.K = 1024; p.aPanelsZ = 16; p.ldc = 32000; p.alpha = 1.f;
      run_gemm(stream, false, false, p, 250, 16, 1); }
    finalize_aux<<<1, 1, 0, stream>>>(AUXB, out);
}

// Round 6
// 2208.913 us; speedup vs baseline: 1.0752x; 1.0752x over previous
//
#include <hip/hip_runtime.h>
#include <math.h>

#define DEV __device__ __forceinline__

using v8s = __attribute__((ext_vector_type(8))) short;   // 8 bf16 (4 VGPRs)
using v4f = __attribute__((ext_vector_type(4))) float;   // 4 fp32 acc

// ---------- bf16 helpers (RNE) ----------
DEV short f2bf(float f) {
    unsigned u = __float_as_uint(f);
    unsigned r = (u + 0x7fffu + ((u >> 16) & 1u)) >> 16;
    return (short)(unsigned short)r;
}
DEV float bf2f(short s) {
    return __uint_as_float(((unsigned)(unsigned short)s) << 16);
}

// async global->LDS, 16B per lane; dest = wave-uniform base + lane*16
DEV void gload16(const short* g, short* l) {
    __builtin_amdgcn_global_load_lds((const __attribute__((address_space(1))) void*)g,
                                     (__attribute__((address_space(3))) void*)l,
                                     16, 0, 0);
}

DEV void raw_barrier() { asm volatile("s_barrier" ::: "memory"); }

// ---------- block reductions (256 threads = 4 waves) ----------
DEV float block_sum256(float v, float* red) {
    __syncthreads();
#pragma unroll
    for (int o = 32; o >= 1; o >>= 1) v += __shfl_down(v, o, 64);
    if ((threadIdx.x & 63) == 0) red[threadIdx.x >> 6] = v;
    __syncthreads();
    return red[0] + red[1] + red[2] + red[3];
}
DEV float block_max256(float v, float* red) {
    __syncthreads();
#pragma unroll
    for (int o = 32; o >= 1; o >>= 1) v = fmaxf(v, __shfl_down(v, o, 64));
    if ((threadIdx.x & 63) == 0) red[threadIdx.x >> 6] = v;
    __syncthreads();
    return fmaxf(fmaxf(red[0], red[1]), fmaxf(red[2], red[3]));
}

// ---------------- model constants ----------------
// V=32000 D=1024 L=2 H=16 KVH=4 HD=64 E=8 FF=2048 K=2 B=2 S=1024

// ---------------- weight conversion to TILED layout ----------------
// element (n,k): panel=chunkMap(n)/128, dst = panel*128*K + (k/32)*4096 + ((k%32)/8)*1024 + (n%128)*8 + k%8
__global__ __launch_bounds__(256) void conv_tile(const float* __restrict__ src,
                                                 short* __restrict__ hi, short* __restrict__ lo,
                                                 long nGroups, int Kg, long chunkRows, long chunkPanelStride) {
    const long panelElems = 128L * Kg * 8;
    for (long idx = (long)blockIdx.x * 256 + threadIdx.x; idx < nGroups; idx += (long)gridDim.x * 256) {
        long rrow = idx / Kg; int g = (int)(idx - rrow * Kg);
        long c = rrow / chunkRows; int ri = (int)(rrow - c * chunkRows);
        long panel = c * chunkPanelStride + (ri >> 7);
        long dst = panel * panelElems + ((long)(g >> 2) << 12) + ((long)(g & 3) << 10) + ((long)(ri & 127) << 3);
        const float4 f0 = ((const float4*)src)[idx * 2];
        const float4 f1 = ((const float4*)src)[idx * 2 + 1];
        short h0 = f2bf(f0.x), h1 = f2bf(f0.y), h2 = f2bf(f0.z), h3 = f2bf(f0.w);
        short h4 = f2bf(f1.x), h5 = f2bf(f1.y), h6 = f2bf(f1.z), h7 = f2bf(f1.w);
        *(ushort4*)(hi + dst)     = make_ushort4((unsigned short)h0, (unsigned short)h1,
                                                 (unsigned short)h2, (unsigned short)h3);
        *(ushort4*)(hi + dst + 4) = make_ushort4((unsigned short)h4, (unsigned short)h5,
                                                 (unsigned short)h6, (unsigned short)h7);
        if (lo) {
            short l0 = f2bf(f0.x - bf2f(h0)), l1 = f2bf(f0.y - bf2f(h1));
            short l2 = f2bf(f0.z - bf2f(h2)), l3 = f2bf(f0.w - bf2f(h3));
            short l4 = f2bf(f1.x - bf2f(h4)), l5 = f2bf(f1.y - bf2f(h5));
            short l6 = f2bf(f1.z - bf2f(h6)), l7 = f2bf(f1.w - bf2f(h7));
            *(ushort4*)(lo + dst)     = make_ushort4((unsigned short)l0, (unsigned short)l1,
                                                     (unsigned short)l2, (unsigned short)l3);
            *(ushort4*)(lo + dst + 4) = make_ushort4((unsigned short)l4, (unsigned short)l5,
                                                     (unsigned short)l6, (unsigned short)l7);
        }
    }
}

// ---------------- generic GEMM ----------------
// C[M,N] = A[M,K] * B[N,K]^T, bf16 hi(+lo) planes, fp32 accum.
// A: tiled (gload, 2-deep pipelined) unless AREG (row-major reg-staged, for PV). B: always tiled.
struct GemmP {
    const short* Ah; const short* Al;
    const short* Bh; const short* Bl;
    float* C; short* Ch; short* Cl;
    const int* cnt; const int* ppd; const int* lrow;
    long aPanelsZ;            // A panels per z (tiled, non-grouped)
    long strideAz;            // AREG: A elems per z
    long strideBz, strideCz;
    int M, N, K, lda, ldc;
    float alpha;
    int outMode;    // 0 store f32, 1 C += alpha*acc, 3 split-bf16 TILED attn store (Ch/Cl)
    int gqaB;       // B z-offset uses GQA mapping (z=b*16+h -> b*4+h/4)
    int grouped;    // 0 none; 1: A panels at ppd[z]>>7, C row = ppd[z]+m; 2: A same, C row = lrow[z*2048+m]
    int causalSkip; // skip blocks with nt > mt
    int causalK;    // limit K loop to (mt+1)*128
    int ntiles, S, G; // group decode: group=(nt,z), member=mt; S=mtiles, G=ntiles*zdim
};

template<bool SPLIT, bool AREG>
__global__ __launch_bounds__(256) void gemm_bt(GemmP p) {
    // ---- XCD-group decode: all members (mt) of one B-panel group on one XCD ----
    const int lid = blockIdx.x;
    const int xcd = lid & 7, sI = lid >> 3;
    const int gi = xcd + 8 * (sI / p.S);
    if (gi >= p.G) return;
    const int mt = sI % p.S;
    const int nt = gi % p.ntiles;
    const int z  = gi / p.ntiles;
    if (p.causalSkip && nt > mt) return;

    const int tid = threadIdx.x;

    int Mz = p.grouped ? p.cnt[z] : p.M;
    if (mt * 128 >= Mz) return;

    long bOff;
    if (p.gqaB) { int b = z >> 4, h = z & 15; bOff = (long)(b * 4 + (h >> 2)) * p.strideBz; }
    else bOff = (long)z * p.strideBz;

    extern __shared__ char smem[];
    short* s0 = (short*)smem;
    // pipelined layout per buffer (shorts): A[4096] B[4096] (Al[4096] Bl[4096])
    const int BUF = SPLIT ? 16384 : 8192;

    const int lane = tid & 63, w = tid >> 6;
    const int lr = lane & 15, lg = lane >> 4;
    const int wr = w >> 1, wc = w & 1;

    v4f acc[4][4];
#pragma unroll
    for (int i = 0; i < 4; ++i)
#pragma unroll
        for (int j = 0; j < 4; ++j) { acc[i][j][0] = 0.f; acc[i][j][1] = 0.f; acc[i][j][2] = 0.f; acc[i][j][3] = 0.f; }

    // ---- B gload pointers (tiled): wave w stages kg=w ----
    const short* bks  = p.Bh + bOff + (long)nt * 128 * p.K + (long)w * 1024 + lane * 8;
    const short* bksL = SPLIT ? p.Bl + bOff + (long)nt * 128 * p.K + (long)w * 1024 + lane * 8 : nullptr;

    // ---- A pointers ----
    const short *aks = nullptr, *aksL = nullptr;     // tiled path
    const short *aH = nullptr, *aL = nullptr;        // AREG path
    short *sA0 = nullptr, *sA1 = nullptr, *sA0l = nullptr, *sA1l = nullptr;
    if constexpr (AREG) {
        const int r = tid & 127;
        const int kgA = tid >> 7;
        int am = mt * 128 + r; if (am >= Mz) am = Mz - 1;
        long arowoff = (long)z * p.strideAz + (long)am * p.lda;
        aH = p.Ah + arowoff + kgA * 16;
        aL = SPLIT ? p.Al + arowoff + kgA * 16 : nullptr;
        sA0 = s0 + (kgA * 256 + r) * 8; sA1 = sA0 + 1024;
        sA0l = s0 + 8192 + (kgA * 256 + r) * 8; sA1l = sA0l + 1024;
    } else {
        long aPanel = (p.grouped ? (long)(p.ppd[z] >> 7) : (long)z * p.aPanelsZ) + mt;
        aks  = p.Ah + aPanel * 128L * p.K + (long)w * 1024 + lane * 8;
        aksL = SPLIT ? p.Al + aPanel * 128L * p.K + (long)w * 1024 + lane * 8 : nullptr;
    }

    const int kEnd = p.causalK ? min(p.K, (mt + 1) * 128) : p.K;

    if constexpr (!AREG) {
        // ================= 2-deep pipelined path =================
        const int nIter = kEnd >> 5;
        const int wb = w * 1024;
        // prologue: stage iter 0 into buf 0
        {
            const long kb = 0;
            short* base = s0;
            gload16(aks + kb,       base + wb);
            gload16(aks + kb + 512, base + wb + 512);
            gload16(bks + kb,       base + 4096 + wb);
            gload16(bks + kb + 512, base + 4096 + wb + 512);
            if (SPLIT) {
                gload16(aksL + kb,       base + 8192 + wb);
                gload16(aksL + kb + 512, base + 8192 + wb + 512);
                gload16(bksL + kb,       base + 12288 + wb);
                gload16(bksL + kb + 512, base + 12288 + wb + 512);
            }
        }
        for (int i = 0; i < nIter; ++i) {
            const int cur = i & 1;
            if (i + 1 < nIter) {
                raw_barrier();                       // all waves done reading buf cur^1
                const long kb = (long)(i + 1) * 4096;
                short* base = s0 + (cur ^ 1) * BUF;
                gload16(aks + kb,       base + wb);
                gload16(aks + kb + 512, base + wb + 512);
                gload16(bks + kb,       base + 4096 + wb);
                gload16(bks + kb + 512, base + 4096 + wb + 512);
                if (SPLIT) {
                    gload16(aksL + kb,       base + 8192 + wb);
                    gload16(aksL + kb + 512, base + 8192 + wb + 512);
                    gload16(bksL + kb,       base + 12288 + wb);
                    gload16(bksL + kb + 512, base + 12288 + wb + 512);
                }
                if constexpr (SPLIT) asm volatile("s_waitcnt vmcnt(8)" ::: "memory");
                else                 asm volatile("s_waitcnt vmcnt(4)" ::: "memory");
            } else {
                asm volatile("s_waitcnt vmcnt(0)" ::: "memory");
            }
            raw_barrier();                           // everyone's buf[cur] loads landed
            const short* base = s0 + cur * BUF;
            const int abase = lg * 1024 + (wr * 64 + lr) * 8;
            const int bbase = 4096 + lg * 1024 + (wc * 64 + lr) * 8;
            v8s ah[4], bh[4];
#pragma unroll
            for (int q = 0; q < 4; ++q) {
                ah[q] = *(const v8s*)(base + abase + q * 128);
                bh[q] = *(const v8s*)(base + bbase + q * 128);
            }
            if constexpr (SPLIT) {
                v8s al[4], bl[4];
#pragma unroll
                for (int q = 0; q < 4; ++q) {
                    al[q] = *(const v8s*)(base + 8192 + abase + q * 128);
                    bl[q] = *(const v8s*)(base + 8192 + bbase + q * 128);
                }
#pragma unroll
                for (int mi = 0; mi < 4; ++mi)
#pragma unroll
                    for (int nj = 0; nj < 4; ++nj) {
                        acc[mi][nj] = __builtin_amdgcn_mfma_f32_16x16x32_bf16(ah[mi], bh[nj], acc[mi][nj], 0, 0, 0);
                        acc[mi][nj] = __builtin_amdgcn_mfma_f32_16x16x32_bf16(al[mi], bh[nj], acc[mi][nj], 0, 0, 0);
                        acc[mi][nj] = __builtin_amdgcn_mfma_f32_16x16x32_bf16(ah[mi], bl[nj], acc[mi][nj], 0, 0, 0);
                    }
            } else {
#pragma unroll
                for (int mi = 0; mi < 4; ++mi)
#pragma unroll
                    for (int nj = 0; nj < 4; ++nj)
                        acc[mi][nj] = __builtin_amdgcn_mfma_f32_16x16x32_bf16(ah[mi], bh[nj], acc[mi][nj], 0, 0, 0);
            }
        }
    } else {
        // ================= legacy AREG path (PV) =================
        short* Ahs = s0;                    // [4][128][8]
        short* Bhs = s0 + 4096;
        short* Als = s0 + 8192;
        short* Bls = s0 + 12288;
        const int wb = w * 1024;
        for (int k0 = 0; k0 < kEnd; k0 += 32) {
            const long kb = (long)k0 * 128;
            uint4 a0 = *(const uint4*)(aH + k0);
            uint4 a1 = *(const uint4*)(aH + k0 + 8);
            uint4 a0l, a1l;
            if (SPLIT) { a0l = *(const uint4*)(aL + k0); a1l = *(const uint4*)(aL + k0 + 8); }
            __syncthreads();
            gload16(bks + kb,       Bhs + wb);
            gload16(bks + kb + 512, Bhs + wb + 512);
            if (SPLIT) {
                gload16(bksL + kb,       Bls + wb);
                gload16(bksL + kb + 512, Bls + wb + 512);
            }
            *(uint4*)sA0 = a0; *(uint4*)sA1 = a1;
            if (SPLIT) { *(uint4*)sA0l = a0l; *(uint4*)sA1l = a1l; }
            __syncthreads();
            const int abase = lg * 1024 + (wr * 64 + lr) * 8;
            const int bbase = lg * 1024 + (wc * 64 + lr) * 8;
            v8s ah[4], bh[4];
#pragma unroll
            for (int q = 0; q < 4; ++q) {
                ah[q] = *(const v8s*)(Ahs + abase + q * 128);
                bh[q] = *(const v8s*)(Bhs + bbase + q * 128);
            }
            if constexpr (SPLIT) {
                v8s al[4], bl[4];
#pragma unroll
                for (int q = 0; q < 4; ++q) {
                    al[q] = *(const v8s*)(Als + abase + q * 128);
                    bl[q] = *(const v8s*)(Bls + bbase + q * 128);
                }
#pragma unroll
                for (int mi = 0; mi < 4; ++mi)
#pragma unroll
                    for (int nj = 0; nj < 4; ++nj) {
                        acc[mi][nj] = __builtin_amdgcn_mfma_f32_16x16x32_bf16(ah[mi], bh[nj], acc[mi][nj], 0, 0, 0);
                        acc[mi][nj] = __builtin_amdgcn_mfma_f32_16x16x32_bf16(al[mi], bh[nj], acc[mi][nj], 0, 0, 0);
                        acc[mi][nj] = __builtin_amdgcn_mfma_f32_16x16x32_bf16(ah[mi], bl[nj], acc[mi][nj], 0, 0, 0);
                    }
            } else {
#pragma unroll
                for (int mi = 0; mi < 4; ++mi)
#pragma unroll
                    for (int nj = 0; nj < 4; ++nj)
                        acc[mi][nj] = __builtin_amdgcn_mfma_f32_16x16x32_bf16(ah[mi], bh[nj], acc[mi][nj], 0, 0, 0);
            }
        }
    }

    // ---- epilogue: D[row=(lane>>4)*4+r][col=lane&15] ----
#pragma unroll
    for (int mi = 0; mi < 4; ++mi) {
        const int mrow = mt * 128 + wr * 64 + mi * 16 + lg * 4;
#pragma unroll
        for (int nj = 0; nj < 4; ++nj) {
            const int ncol = nt * 128 + wc * 64 + nj * 16 + lr;
            if (ncol < p.N) {
#pragma unroll
                for (int rr = 0; rr < 4; ++rr) {
                    const int m = mrow + rr;
                    if (m < Mz) {
                        float v = acc[mi][nj][rr] * p.alpha;
                        if (p.outMode == 3) {
                            int b = z >> 4, h = z & 15;
                            int grow = b * 1024 + m, col = h * 64 + ncol;
                            long dst = ((long)(grow >> 7)) * 131072 + ((long)(col >> 5) << 12)
                                     + ((long)((col >> 3) & 3) << 10) + ((long)(grow & 127) << 3) + (col & 7);
                            short hi = f2bf(v);
                            p.Ch[dst] = hi;
                            p.Cl[dst] = f2bf(v - bf2f(hi));
                        } else {
                            long crow;
                            if (p.grouped == 1)      crow = p.ppd[z] + m;
                            else if (p.grouped == 2) crow = p.lrow[z * 2048 + m];
                            else                     crow = m;
                            long co = (long)z * p.strideCz + crow * (long)p.ldc + ncol;
                            if (p.outMode == 0) p.C[co] = v;
                            else                p.C[co] += v;
                        }
                    }
                }
            }
        }
    }
}

// ---------------- small kernels ----------------
__global__ __launch_bounds__(256) void embed_kernel(const int* toks, const float* emb, float* X) {
    const int t = blockIdx.x;
    const int tok = toks[t];
    const float4* s = (const float4*)(emb + (size_t)tok * 1024);
    float4* d = (float4*)(X + (size_t)t * 1024);
    d[threadIdx.x] = s[threadIdx.x];
}

// rmsnorm -> TILED split output (K=1024, panels of 128 rows)
__global__ __launch_bounds__(256) void rmsnorm_split(const float* X, const float* w, short* oh, short* ol) {
    __shared__ float red[4];
    const long t = blockIdx.x;
    const float* r = X + t * 1024;
    float ss = 0.f;
    for (int j = threadIdx.x; j < 1024; j += 256) { float f = r[j]; ss += f * f; }
    ss = block_sum256(ss, red);
    const float sc = 32.f / fmaxf(sqrtf(ss), 1e-6f);
    if (threadIdx.x < 128) {
        const int g = threadIdx.x, f = g * 8;
        float v[8];
#pragma unroll
        for (int j = 0; j < 8; ++j) v[j] = r[f + j] * sc * w[f + j];
        long dst = (t >> 7) * 131072 + ((long)(g >> 2) << 12) + ((long)(g & 3) << 10) + ((t & 127) << 3);
        short h[8], lo[8];
#pragma unroll
        for (int j = 0; j < 8; ++j) { h[j] = f2bf(v[j]); lo[j] = f2bf(v[j] - bf2f(h[j])); }
        *(ushort4*)(oh + dst)     = make_ushort4((unsigned short)h[0], (unsigned short)h[1], (unsigned short)h[2], (unsigned short)h[3]);
        *(ushort4*)(oh + dst + 4) = make_ushort4((unsigned short)h[4], (unsigned short)h[5], (unsigned short)h[6], (unsigned short)h[7]);
        *(ushort4*)(ol + dst)     = make_ushort4((unsigned short)lo[0], (unsigned short)lo[1], (unsigned short)lo[2], (unsigned short)lo[3]);
        *(ushort4*)(ol + dst + 4) = make_ushort4((unsigned short)lo[4], (unsigned short)lo[5], (unsigned short)lo[6], (unsigned short)lo[7]);
    }
}

struct RopeF { float f[32]; };

// Q-hat -> TILED per z (8 panels, K=64)
__global__ __launch_bounds__(256) void rope_q_kernel(const float* QKV, short* OH, short* OL, RopeF rf) {
    const int idx = blockIdx.x * 256 + threadIdx.x;           // B*S*H*32
    const int pp = idx & 31, h = (idx >> 5) & 15, s = (idx >> 9) & 1023, b = idx >> 19;
    const float* src = QKV + ((size_t)(b * 1024 + s)) * 1536 + h * 64 + 2 * pp;
    const float x0 = src[0], x1 = src[1];
    const float ang = (float)s * rf.f[pp];
    float sn, cs; sincosf(ang, &sn, &cs);
    const float o0 = x0 * cs - x1 * sn, o1 = x0 * sn + x1 * cs;
    const int z = b * 16 + h, d = 2 * pp;
    const long off = (long)z * 65536 + (long)(s >> 7) * 8192
                   + ((long)(d >> 5) << 12) + ((long)((d >> 3) & 3) << 10)
                   + ((long)(s & 127) << 3) + (d & 7);
    short h0 = f2bf(o0); OH[off] = h0; OL[off] = f2bf(o0 - bf2f(h0));
    short h1 = f2bf(o1); OH[off + 1] = h1; OL[off + 1] = f2bf(o1 - bf2f(h1));
}

// K-hat -> TILED per z=b*4+kv (8 panels, K=64)
__global__ __launch_bounds__(256) void rope_k_kernel(const float* QKV, short* KH, short* KL, RopeF rf) {
    const int idx = blockIdx.x * 256 + threadIdx.x;           // B*S*KVH*32
    const int pp = idx & 31, kv = (idx >> 5) & 3, s = (idx >> 7) & 1023, b = idx >> 17;
    const float* src = QKV + ((size_t)(b * 1024 + s)) * 1536 + 1024 + kv * 64 + 2 * pp;
    const float x0 = src[0], x1 = src[1];
    const float ang = (float)s * rf.f[pp];
    float sn, cs; sincosf(ang, &sn, &cs);
    const float o0 = x0 * cs - x1 * sn, o1 = x0 * sn + x1 * cs;
    const int z = b * 4 + kv, d = 2 * pp;
    const long off = (long)z * 65536 + (long)(s >> 7) * 8192
                   + ((long)(d >> 5) << 12) + ((long)((d >> 3) & 3) << 10)
                   + ((long)(s & 127) << 3) + (d & 7);
    short h0 = f2bf(o0); KH[off] = h0; KL[off] = f2bf(o0 - bf2f(h0));
    short h1 = f2bf(o1); KH[off + 1] = h1; KL[off + 1] = f2bf(o1 - bf2f(h1));
}

// V^T -> TILED per z: one padded 128-row panel, K=1024 (rows 64..127 zero)
__global__ __launch_bounds__(256) void transpose_v_kernel(const float* QKV, short* VH, short* VL) {
    const int idx = blockIdx.x * 256 + threadIdx.x;           // B*S*KVH*HD
    const int d = idx & 63, kv = (idx >> 6) & 3, s = (idx >> 8) & 1023, b = idx >> 18;
    const float f = QKV[((size_t)(b * 1024 + s)) * 1536 + 1280 + kv * 64 + d];
    const int z = b * 4 + kv;
    const long off = (long)z * 131072 + ((long)(s >> 5) << 12) + ((long)((s >> 3) & 3) << 10)
                   + ((long)d << 3) + (s & 7);
    short hi = f2bf(f);
    VH[off] = hi; VL[off] = f2bf(f - bf2f(hi));
    VH[off + 512] = 0; VL[off + 512] = 0;     // pad row d+64
}

// softmax in-place: row-major P hi|lo planes interleaved per row (lda 2048)
__global__ __launch_bounds__(256) void attn_softmax(float* SC) {
    const long row = blockIdx.x;                 // z*1024 + i
    const int i = (int)(row & 1023);
    float* r = SC + row * 1024;
    __shared__ float buf[1024];
    __shared__ float red[4];
    const int n = i + 1;
    for (int j = threadIdx.x; j < 1024; j += 256) buf[j] = r[j];
    __syncthreads();
    float m = -INFINITY;
    for (int j = threadIdx.x; j < n; j += 256) m = fmaxf(m, buf[j]);
    m = block_max256(m, red);
    float s = 0.f;
    for (int j = threadIdx.x; j < n; j += 256) { float e = expf(buf[j] - m); buf[j] = e; s += e; }
    s = block_sum256(s, red);
    const float inv = 1.f / s;
    short* rh = (short*)r;
    short* rl = rh + 1024;
    __syncthreads();
    for (int j = threadIdx.x; j < 1024; j += 256) {
        float pv = (j < n) ? buf[j] * inv : 0.f;
        short hi = f2bf(pv);
        rh[j] = hi;
        rl[j] = f2bf(pv - bf2f(hi));
    }
}

__global__ __launch_bounds__(256) void router_kernel(const float* X, const float* wn, const float* rw,
                                                     float* probs, float* lse, int* cnt, int* ltok, int* lrow) {
    __shared__ float xs[1024];
    __shared__ float red[4];
    __shared__ float lg[8];
    const int t = blockIdx.x;
    const float* r = X + (size_t)t * 1024;
    for (int j = threadIdx.x; j < 1024; j += 256) xs[j] = r[j];
    __syncthreads();
    float ss = 0.f;
    for (int j = threadIdx.x; j < 1024; j += 256) ss += xs[j] * xs[j];
    ss = block_sum256(ss, red);
    const float sc = 32.f / fmaxf(sqrtf(ss), 1e-6f);
    float acc[8] = {0, 0, 0, 0, 0, 0, 0, 0};
    for (int j = threadIdx.x; j < 1024; j += 256) {
        const float xv = xs[j] * wn[j];
#pragma unroll
        for (int e = 0; e < 8; ++e) acc[e] += xv * rw[e * 1024 + j];
    }
#pragma unroll
    for (int e = 0; e < 8; ++e) {
        float s = block_sum256(acc[e], red);
        if (threadIdx.x == 0) lg[e] = s * sc;
    }
    __syncthreads();
    if (threadIdx.x == 0) {
        float m = lg[0];
        for (int e = 1; e < 8; ++e) m = fmaxf(m, lg[e]);
        float ex[8], se = 0.f;
        for (int e = 0; e < 8; ++e) { ex[e] = expf(lg[e] - m); se += ex[e]; }
        const float inv = 1.f / se;
        float pr[8];
        for (int e = 0; e < 8; ++e) { pr[e] = ex[e] * inv; probs[(size_t)t * 8 + e] = pr[e]; }
        lse[t] = m + logf(se);
        int i1 = 0;
        for (int e = 1; e < 8; ++e) if (pr[e] > pr[i1]) i1 = e;
        int i2 = (i1 == 0) ? 1 : 0;
        for (int e = 0; e < 8; ++e) if (e != i1 && pr[e] > pr[i2]) i2 = e;
        int s1 = atomicAdd(&cnt[i1], 1); ltok[i1 * 2048 + s1] = t; lrow[i1 * 2048 + s1] = 2 * t;
        int s2 = atomicAdd(&cnt[i2], 1); ltok[i2 * 2048 + s2] = t; lrow[i2 * 2048 + s2] = 2 * t + 1;
    }
}

__global__ void prefix_kernel(const int* cnt, int* ppd) {
    if (threadIdx.x == 0 && blockIdx.x == 0) {
        int a = 0;
        for (int e = 0; e < 8; ++e) { ppd[e] = a; a += ((cnt[e] + 127) >> 7) << 7; }
    }
}

// gather XN (tiled) rows -> per-expert padded tiled GXN
__global__ __launch_bounds__(256) void gather_kernel(const short* XNH, const short* XNL,
                                                     const int* cnt, const int* ppd, const int* ltok,
                                                     short* GXNH, short* GXNL) {
    const int e = blockIdx.y, i = blockIdx.x;
    if (i >= cnt[e]) return;
    const int t = ltok[e * 2048 + i];
    const int pd = ppd[e] + i;
    const int plane = threadIdx.x >> 7, g = threadIdx.x & 127;
    const long goff = ((long)(g >> 2) << 12) + ((long)(g & 3) << 10);
    const long src = (long)(t >> 7) * 131072 + goff + ((t & 127) << 3);
    const long dst = (long)(pd >> 7) * 131072 + goff + ((pd & 127) << 3);
    const short* S = plane ? XNL : XNH;
    short* D = plane ? GXNL : GXNH;
    *(uint4*)(D + dst) = *(const uint4*)(S + src);
}

// silu(u)*g over padded U rows [5120][4096] -> tiled split H (K=2048)
__global__ __launch_bounds__(256) void silu_mul(const float* U, short* HH, short* HL) {
    const int row = blockIdx.x, g = threadIdx.x;   // 5120 blocks, 256 groups
    const float* ur = U + (long)row * 4096 + g * 8;
    const float4 u0 = *(const float4*)ur, u1 = *(const float4*)(ur + 4);
    const float4 g0 = *(const float4*)(ur + 2048), g1 = *(const float4*)(ur + 2052);
    float h[8];
    h[0] = (u0.x / (1.f + expf(-u0.x))) * g0.x;
    h[1] = (u0.y / (1.f + expf(-u0.y))) * g0.y;
    h[2] = (u0.z / (1.f + expf(-u0.z))) * g0.z;
    h[3] = (u0.w / (1.f + expf(-u0.w))) * g0.w;
    h[4] = (u1.x / (1.f + expf(-u1.x))) * g1.x;
    h[5] = (u1.y / (1.f + expf(-u1.y))) * g1.y;
    h[6] = (u1.z / (1.f + expf(-u1.z))) * g1.z;
    h[7] = (u1.w / (1.f + expf(-u1.w))) * g1.w;
    const long dst = (long)(row >> 7) * 262144 + ((long)(g >> 2) << 12) + ((long)(g & 3) << 10) + ((row & 127) << 3);
    short hh[8], ll[8];
#pragma unroll
    for (int j = 0; j < 8; ++j) { hh[j] = f2bf(h[j]); ll[j] = f2bf(h[j] - bf2f(hh[j])); }
    *(ushort4*)(HH + dst)     = make_ushort4((unsigned short)hh[0], (unsigned short)hh[1], (unsigned short)hh[2], (unsigned short)hh[3]);
    *(ushort4*)(HH + dst + 4) = make_ushort4((unsigned short)hh[4], (unsigned short)hh[5], (unsigned short)hh[6], (unsigned short)hh[7]);
    *(ushort4*)(HL + dst)     = make_ushort4((unsigned short)ll[0], (unsigned short)ll[1], (unsigned short)ll[2], (unsigned short)ll[3]);
    *(ushort4*)(HL + dst + 4) = make_ushort4((unsigned short)ll[4], (unsigned short)ll[5], (unsigned short)ll[6], (unsigned short)ll[7]);
}

__global__ __launch_bounds__(256) void combine_kernel(float* X, const float* Y) {
    const int i4 = blockIdx.x * 256 + threadIdx.x;            // 2048*1024/4
    const int t = i4 >> 8, d4 = i4 & 255;
    float4 x = ((float4*)X)[i4];
    const float4 a = ((const float4*)Y)[(size_t)(2 * t) * 256 + d4];
    const float4 b = ((const float4*)Y)[(size_t)(2 * t + 1) * 256 + d4];
    x.x += a.x + b.x; x.y += a.y + b.y; x.z += a.z + b.z; x.w += a.w + b.w;
    ((float4*)X)[i4] = x;
}

__global__ __launch_bounds__(256) void aux_kernel(const float* probs, const float* lse, float* auxb, int layer) {
    __shared__ float red[4];
    float sl = 0.f;
    for (int t = threadIdx.x; t < 2048; t += 256) sl += lse[t];
    sl = block_sum256(sl, red);
    float s1 = 0.f, s2 = 0.f;
    for (int i = threadIdx.x; i < 8192; i += 256) {
        const float l = probs[i] + probs[8192 + i];
        s1 += l; s2 += l * l;
    }
    s1 = block_sum256(s1, red);
    s2 = block_sum256(s2, red);
    if (threadIdx.x == 0) {
        const float ml = sl / 2048.f;
        const float mean = s1 / 8192.f;
        const float var = fmaxf((s2 - s1 * s1 / 8192.f) / 8191.f, 0.f);
        auxb[layer] = 0.001f * (ml * ml + var / (mean * mean));
    }
}

__global__ void finalize_aux(const float* auxb, float* out) {
    if (threadIdx.x == 0 && blockIdx.x == 0)
        out[(size_t)2 * 1024 * 32000] = auxb[0] + auxb[1];
}

// ---------------- launch helpers ----------------
static void run_gemm(hipStream_t s, bool split, bool areg, GemmP& p, int ntiles, int mtiles, int zdim) {
    p.ntiles = ntiles; p.S = mtiles;
    p.G = ntiles * zdim;
    int Gp = (p.G + 7) & ~7;
    long nb = (long)Gp * mtiles;
    dim3 g((unsigned)nb, 1, 1), b(256);
    size_t lds = areg ? (split ? 32768 : 16384) : (split ? 65536 : 32768);
    if (split) {
        if (areg) gemm_bt<true, true><<<g, b, lds, s>>>(p);
        else      gemm_bt<true, false><<<g, b, lds, s>>>(p);
    } else {
        if (areg) gemm_bt<false, true><<<g, b, lds, s>>>(p);
        else      gemm_bt<false, false><<<g, b, lds, s>>>(p);
    }
}

static void run_tile(hipStream_t s, const float* src, short* hi, short* lo,
                     long rows, int K, long chunkRows, long chunkPanelStride) {
    long groups = rows * (K / 8);
    long nb = (groups + 255) / 256; if (nb > 2048) nb = 2048;
    conv_tile<<<(unsigned)nb, 256, 0, s>>>(src, hi, lo, groups, K / 8, chunkRows, chunkPanelStride);
}

extern "C" void kernel_launch(void* const* d_in, const int* in_sizes, int n_in,
                              void* d_out, int out_size, void* d_ws, size_t ws_size,
                              hipStream_t stream) {
    (void)in_sizes; (void)n_in; (void)out_size; (void)ws_size;
    const int*   tokens = (const int*)d_in[0];
    const float* tok_emb = (const float*)d_in[1];
    const float* norm1 = (const float*)d_in[2];
    const float* norm2 = (const float*)d_in[3];
    const float* wq = (const float*)d_in[4];
    const float* wk = (const float*)d_in[5];
    const float* wv = (const float*)d_in[6];
    const float* wo = (const float*)d_in[7];
    const float* rw = (const float*)d_in[8];
    const float* w1 = (const float*)d_in[9];
    const float* w2 = (const float*)d_in[10];
    const float* w3 = (const float*)d_in[11];
    const float* normf = (const float*)d_in[12];
    const float* headw = (const float*)d_in[13];
    float* out = (float*)d_out;

    char* w = (char*)d_ws;
    const size_t MB = 1024ull * 1024ull;
    float* X    = (float*)(w + 0);            // 8 MB residual fp32
    short* XNH  = (short*)(w + 8 * MB);       // tiled, 16 panels
    short* XNL  = (short*)(w + 12 * MB);
    short* QRH  = (short*)(w + 16 * MB);      // tiled Q-hat; aliased as AO tiled after QK^T
    short* QRL  = (short*)(w + 20 * MB);
    short* AOH  = QRH;
    short* AOL  = QRL;
    short* KRH  = (short*)(w + 24 * MB);      // 1 MB tiled
    short* KRL  = (short*)(w + 25 * MB);
    short* VTH  = (short*)(w + 26 * MB);      // 2 MB tiled padded
    short* VTL  = (short*)(w + 28 * MB);
    // BIG union region 32..168 MB:
    float* QKV  = (float*)(w + 32 * MB);      // 12 MB
    float* SC   = (float*)(w + 32 * MB);      // 128 MB scores / P planes in place
    float* U    = (float*)(w + 32 * MB);      // 80 MB padded [5120][4096]
    short* HH   = (short*)(w + 112 * MB);     // 20 MB tiled padded
    short* HL   = (short*)(w + 132 * MB);     // 20 MB
    float* Y    = (float*)(w + 152 * MB);     // 16 MB
    short* GXNH = (short*)(w + 168 * MB);     // 10 MB gathered tiled padded
    short* GXNL = (short*)(w + 178 * MB);     // 10 MB
    float* PROBS= (float*)(w + 188 * MB);               // 64 KB
    float* LSE  = (float*)(w + 188 * MB + 65536);       // 8 KB
    int*   CNT  = (int*)  (w + 188 * MB + 73728);
    int*   PPD  = (int*)  (w + 188 * MB + 73856);
    int*   LTOK = (int*)  (w + 188 * MB + 74240);       // 64 KB
    int*   LROW = (int*)  (w + 188 * MB + 74240 + 65536);
    float* AUXB = (float*)(w + 188 * MB + 74240 + 131072);
    // converted weights (all TILED):
    short* WQKVH = (short*)(w + 190 * MB);    // 6 MB
    short* WQKVL = (short*)(w + 196 * MB);    // 6 MB
    short* WOH   = (short*)(w + 202 * MB);    // 4 MB
    short* WOL   = (short*)(w + 206 * MB);    // 4 MB
    short* W12H  = (short*)(w + 210 * MB);    // 64 MB per-layer
    short* W12L  = (short*)(w + 274 * MB);    // 64 MB (layer 0 only; head aliases after)
    short* W3H   = (short*)(w + 338 * MB);    // 32 MB per-layer
    short* W3L   = (short*)(w + 370 * MB);    // 32 MB (layer 0 only)
    short* HDH   = (short*)(w + 274 * MB);    // 62.5 MB, aliases W12L (dead after l0 MoE)
    // total ~402 MB

    RopeF rf;
    for (int i = 0; i < 32; ++i) {
        float t = (float)pow(10000.0, (double)(2 * i) / 64.0);
        rf.f[i] = 1.0f / t;
    }

    // ---- weight conversion to tiled layout ----
    for (int l = 0; l < 2; ++l) {
        long qo = (long)l * 1572864;
        run_tile(stream, wq + (long)l * 1048576, WQKVH + qo,           WQKVL + qo,           1024, 1024, 1024, 8);
        run_tile(stream, wk + (long)l * 262144,  WQKVH + qo + 1048576, WQKVL + qo + 1048576, 256, 1024, 256, 2);
        run_tile(stream, wv + (long)l * 262144,  WQKVH + qo + 1310720, WQKVL + qo + 1310720, 256, 1024, 256, 2);
    }
    run_tile(stream, wo, WOH, WOL, 2048, 1024, 2048, 16);

    embed_kernel<<<2048, 256, 0, stream>>>(tokens, tok_emb, X);

    for (int l = 0; l < 2; ++l) {
        const bool msp = (l == 0);   // layer-0 MoE feeds layer-1 router -> split precision
        run_tile(stream, w1 + (long)l * 16777216, W12H,           msp ? W12L : nullptr,           16384, 1024, 2048, 32);
        run_tile(stream, w2 + (long)l * 16777216, W12H + 2097152, msp ? W12L + 2097152 : nullptr, 16384, 1024, 2048, 32);
        run_tile(stream, w3 + (long)l * 16777216, W3H,            msp ? W3L : nullptr,            8192, 2048, 8192, 64);

        rmsnorm_split<<<2048, 256, 0, stream>>>(X, norm1 + l * 1024, XNH, XNL);

        // fused QKV: [2048][1536] fp32
        { GemmP p = {}; p.Ah = XNH; p.Al = XNL; p.Bh = WQKVH + (long)l * 1572864; p.Bl = WQKVL + (long)l * 1572864;
          p.C = QKV; p.M = 2048; p.N = 1536; p.K = 1024; p.aPanelsZ = 16; p.ldc = 1536; p.alpha = 1.f;
          run_gemm(stream, true, false, p, 12, 16, 1); }

        rope_q_kernel<<<4096, 256, 0, stream>>>(QKV, QRH, QRL, rf);
        rope_k_kernel<<<1024, 256, 0, stream>>>(QKV, KRH, KRL, rf);
        transpose_v_kernel<<<2048, 256, 0, stream>>>(QKV, VTH, VTL);

        // scores = q k^T / 8  (causal tile skip), fp32 into SC
        { GemmP p = {}; p.Ah = QRH; p.Al = QRL; p.Bh = KRH; p.Bl = KRL; p.C = SC;
          p.M = 1024; p.N = 1024; p.K = 64; p.aPanelsZ = 8; p.ldc = 1024;
          p.strideBz = 65536; p.strideCz = 1048576;
          p.alpha = 0.125f; p.gqaB = 1; p.causalSkip = 1;
          run_gemm(stream, true, false, p, 8, 8, 32); }

        attn_softmax<<<32768, 256, 0, stream>>>(SC);

        // PV: A = P(hi|lo in-place, reg-staged), B = V^T tiled; out TILED split AO
        { GemmP p = {}; p.Ah = (short*)SC; p.Al = (short*)SC + 1024; p.Bh = VTH; p.Bl = VTL; p.Ch = AOH; p.Cl = AOL;
          p.M = 1024; p.N = 64; p.K = 1024; p.lda = 2048;
          p.strideAz = 2097152; p.strideBz = 131072;
          p.alpha = 1.f; p.gqaB = 1; p.causalK = 1; p.outMode = 3;
          run_gemm(stream, true, true, p, 1, 8, 32); }

        // x += 0.5 * attno @ wo^T
        { GemmP p = {}; p.Ah = AOH; p.Al = AOL; p.Bh = WOH + (long)l * 1048576; p.Bl = WOL + (long)l * 1048576; p.C = X;
          p.M = 2048; p.N = 1024; p.K = 1024; p.aPanelsZ = 16; p.ldc = 1024;
          p.alpha = 0.5f; p.outMode = 1;
          run_gemm(stream, true, false, p, 8, 16, 1); }

        // ---- MoE ----
        rmsnorm_split<<<2048, 256, 0, stream>>>(X, norm2 + l * 1024, XNH, XNL);
        hipMemsetAsync(CNT, 0, 8 * sizeof(int), stream);
        router_kernel<<<2048, 256, 0, stream>>>(X, norm2 + l * 1024, rw + (size_t)l * 8 * 1024,
                                                PROBS, LSE, CNT, LTOK, LROW);
        prefix_kernel<<<1, 64, 0, stream>>>(CNT, PPD);
        { dim3 gg(2048, 8); gather_kernel<<<gg, 256, 0, stream>>>(XNH, XNL, CNT, PPD, LTOK, GXNH, GXNL); }

        // fused u|g: C rows at padded positions
        { GemmP p = {}; p.Ah = GXNH; p.Al = GXNL; p.Bh = W12H; p.Bl = W12L; p.C = U;
          p.M = 2048; p.N = 4096; p.K = 1024; p.ldc = 4096;
          p.strideBz = 4194304; p.strideCz = 0; p.alpha = 1.f; p.grouped = 1;
          p.cnt = CNT; p.ppd = PPD; p.lrow = LROW;
          run_gemm(stream, msp, false, p, 32, 16, 8); }
        silu_mul<<<5120, 256, 0, stream>>>(U, HH, HL);
        // y = h @ w3^T, scatter rows by lrow into Y
        { GemmP p = {}; p.Ah = HH; p.Al = HL; p.Bh = W3H; p.Bl = W3L; p.C = Y;
          p.M = 2048; p.N = 1024; p.K = 2048; p.ldc = 1024;
          p.strideBz = 2097152; p.strideCz = 0; p.alpha = 1.f; p.grouped = 2;
          p.cnt = CNT; p.ppd = PPD; p.lrow = LROW;
          run_gemm(stream, msp, false, p, 8, 16, 8); }
        combine_kernel<<<2048, 256, 0, stream>>>(X, Y);
        aux_kernel<<<1, 256, 0, stream>>>(PROBS, LSE, AUXB, l);

        if (l == 0) // W12L/W3L dead now: convert head into aliased region
            run_tile(stream, headw, HDH, nullptr, 32000, 1024, 32000, 250);
    }

    rmsnorm_split<<<2048, 256, 0, stream>>>(X, normf, XNH, XNL);
    { GemmP p = {}; p.Ah = XNH; p.Bh = HDH; p.C = out;
      p.M = 2048; p.N = 32000; p.K = 1024; p.aPanelsZ = 16; p.ldc = 32000; p.alpha = 1.f;
      run_gemm(stream, false, false, p, 250, 16, 1); }
    finalize_aux<<<1, 1, 0, stream>>>(AUXB, out);
}

// Round 7
// 2163.617 us; speedup vs baseline: 1.0977x; 1.0209x over previous
//
#include <hip/hip_runtime.h>
#include <math.h>

#define DEV __device__ __forceinline__

using v8s = __attribute__((ext_vector_type(8))) short;   // 8 bf16 (4 VGPRs)
using v4f = __attribute__((ext_vector_type(4))) float;   // 4 fp32 acc

// ---------- bf16 helpers (RNE) ----------
DEV short f2bf(float f) {
    unsigned u = __float_as_uint(f);
    unsigned r = (u + 0x7fffu + ((u >> 16) & 1u)) >> 16;
    return (short)(unsigned short)r;
}
DEV float bf2f(short s) {
    return __uint_as_float(((unsigned)(unsigned short)s) << 16);
}

// async global->LDS: src per-lane (includes lane*8 shorts), dst wave-uniform base; HW adds lane*16B
DEV void gload16(const short* g, short* l) {
    __builtin_amdgcn_global_load_lds((const __attribute__((address_space(1))) void*)g,
                                     (__attribute__((address_space(3))) void*)l,
                                     16, 0, 0);
}

DEV void raw_barrier() { asm volatile("s_barrier" ::: "memory"); }

// ---------- block reductions (256 threads = 4 waves) ----------
DEV float block_sum256(float v, float* red) {
    __syncthreads();
#pragma unroll
    for (int o = 32; o >= 1; o >>= 1) v += __shfl_down(v, o, 64);
    if ((threadIdx.x & 63) == 0) red[threadIdx.x >> 6] = v;
    __syncthreads();
    return red[0] + red[1] + red[2] + red[3];
}
DEV float block_max256(float v, float* red) {
    __syncthreads();
#pragma unroll
    for (int o = 32; o >= 1; o >>= 1) v = fmaxf(v, __shfl_down(v, o, 64));
    if ((threadIdx.x & 63) == 0) red[threadIdx.x >> 6] = v;
    __syncthreads();
    return fmaxf(fmaxf(red[0], red[1]), fmaxf(red[2], red[3]));
}

// ---------------- model constants ----------------
// V=32000 D=1024 L=2 H=16 KVH=4 HD=64 E=8 FF=2048 K=2 B=2 S=1024

// ---------------- weight conversion to TILED layout ----------------
// element (n,k): panel=chunkMap(n)/128, dst = panel*128*K + (k/32)*4096 + ((k%32)/8)*1024 + (n%128)*8 + k%8
__global__ __launch_bounds__(256) void conv_tile(const float* __restrict__ src,
                                                 short* __restrict__ hi, short* __restrict__ lo,
                                                 long nGroups, int Kg, long chunkRows, long chunkPanelStride) {
    const long panelElems = 128L * Kg * 8;
    for (long idx = (long)blockIdx.x * 256 + threadIdx.x; idx < nGroups; idx += (long)gridDim.x * 256) {
        long rrow = idx / Kg; int g = (int)(idx - rrow * Kg);
        long c = rrow / chunkRows; int ri = (int)(rrow - c * chunkRows);
        long panel = c * chunkPanelStride + (ri >> 7);
        long dst = panel * panelElems + ((long)(g >> 2) << 12) + ((long)(g & 3) << 10) + ((long)(ri & 127) << 3);
        const float4 f0 = ((const float4*)src)[idx * 2];
        const float4 f1 = ((const float4*)src)[idx * 2 + 1];
        short h0 = f2bf(f0.x), h1 = f2bf(f0.y), h2 = f2bf(f0.z), h3 = f2bf(f0.w);
        short h4 = f2bf(f1.x), h5 = f2bf(f1.y), h6 = f2bf(f1.z), h7 = f2bf(f1.w);
        *(ushort4*)(hi + dst)     = make_ushort4((unsigned short)h0, (unsigned short)h1,
                                                 (unsigned short)h2, (unsigned short)h3);
        *(ushort4*)(hi + dst + 4) = make_ushort4((unsigned short)h4, (unsigned short)h5,
                                                 (unsigned short)h6, (unsigned short)h7);
        if (lo) {
            short l0 = f2bf(f0.x - bf2f(h0)), l1 = f2bf(f0.y - bf2f(h1));
            short l2 = f2bf(f0.z - bf2f(h2)), l3 = f2bf(f0.w - bf2f(h3));
            short l4 = f2bf(f1.x - bf2f(h4)), l5 = f2bf(f1.y - bf2f(h5));
            short l6 = f2bf(f1.z - bf2f(h6)), l7 = f2bf(f1.w - bf2f(h7));
            *(ushort4*)(lo + dst)     = make_ushort4((unsigned short)l0, (unsigned short)l1,
                                                     (unsigned short)l2, (unsigned short)l3);
            *(ushort4*)(lo + dst + 4) = make_ushort4((unsigned short)l4, (unsigned short)l5,
                                                     (unsigned short)l6, (unsigned short)l7);
        }
    }
}

// ---------------- GEMM params ----------------
struct GemmP {
    const short* Ah; const short* Al;
    const short* Bh; const short* Bl;
    float* C; short* Ch; short* Cl;
    const int* cnt; const int* ppd; const int* lrow;
    long aPanelsZ;            // A panels(128-row) per z (tiled, non-grouped)
    long strideAz;            // PV: A elems per z
    long strideBz, strideCz;
    int M, N, K, lda, ldc;
    float alpha;
    int outMode;    // 0 store f32, 1 C += alpha*acc
    int gqaB;       // B z-offset uses GQA mapping
    int grouped;    // 0 none; 1: A panels at ppd[z]>>7, C row = ppd[z]+m; 2: A same, C row = lrow[z*2048+m]
    int causalSkip;
    int causalK;
    int ntiles, S, G;
};

// ======== BM=128 / BN=128, 256 threads, 2-deep pipeline (proven R6 structure) ========
template<bool SPLIT>
__global__ __launch_bounds__(256) void gemm_bt128(GemmP p) {
    const int lid = blockIdx.x;
    const int xcd = lid & 7, sI = lid >> 3;
    const int gi = xcd + 8 * (sI / p.S);
    if (gi >= p.G) return;
    const int mt = sI % p.S;
    const int nt = gi % p.ntiles;
    const int z  = gi / p.ntiles;
    if (p.causalSkip && nt > mt) return;

    const int tid = threadIdx.x;
    int Mz = p.grouped ? p.cnt[z] : p.M;
    if (mt * 128 >= Mz) return;

    long bOff;
    if (p.gqaB) { int b = z >> 4, h = z & 15; bOff = (long)(b * 4 + (h >> 2)) * p.strideBz; }
    else bOff = (long)z * p.strideBz;

    extern __shared__ short s0[];
    const int BUF = SPLIT ? 16384 : 8192;

    const int lane = tid & 63, w = tid >> 6;
    const int lr = lane & 15, lg = lane >> 4;
    const int wr = w >> 1, wc = w & 1;

    v4f acc[4][4];
#pragma unroll
    for (int i = 0; i < 4; ++i)
#pragma unroll
        for (int j = 0; j < 4; ++j) { acc[i][j][0] = 0.f; acc[i][j][1] = 0.f; acc[i][j][2] = 0.f; acc[i][j][3] = 0.f; }

    const short* bks  = p.Bh + bOff + (long)nt * 128 * p.K + (long)w * 1024 + lane * 8;
    const short* bksL = SPLIT ? p.Bl + bOff + (long)nt * 128 * p.K + (long)w * 1024 + lane * 8 : nullptr;

    long aPanel = (p.grouped ? (long)(p.ppd[z] >> 7) : (long)z * p.aPanelsZ) + mt;
    const short* aks  = p.Ah + aPanel * 128L * p.K + (long)w * 1024 + lane * 8;
    const short* aksL = SPLIT ? p.Al + aPanel * 128L * p.K + (long)w * 1024 + lane * 8 : nullptr;

    const int nIter = p.K >> 5;
    const int wb = w * 1024;
    {
        gload16(aks,       s0 + wb);
        gload16(aks + 512, s0 + wb + 512);
        gload16(bks,       s0 + 4096 + wb);
        gload16(bks + 512, s0 + 4096 + wb + 512);
        if (SPLIT) {
            gload16(aksL,       s0 + 8192 + wb);
            gload16(aksL + 512, s0 + 8192 + wb + 512);
            gload16(bksL,       s0 + 12288 + wb);
            gload16(bksL + 512, s0 + 12288 + wb + 512);
        }
    }
    for (int i = 0; i < nIter; ++i) {
        const int cur = i & 1;
        if (i + 1 < nIter) {
            raw_barrier();
            const long kb = (long)(i + 1) * 4096;
            short* base = s0 + (cur ^ 1) * BUF;
            gload16(aks + kb,       base + wb);
            gload16(aks + kb + 512, base + wb + 512);
            gload16(bks + kb,       base + 4096 + wb);
            gload16(bks + kb + 512, base + 4096 + wb + 512);
            if (SPLIT) {
                gload16(aksL + kb,       base + 8192 + wb);
                gload16(aksL + kb + 512, base + 8192 + wb + 512);
                gload16(bksL + kb,       base + 12288 + wb);
                gload16(bksL + kb + 512, base + 12288 + wb + 512);
            }
            if constexpr (SPLIT) asm volatile("s_waitcnt vmcnt(8)" ::: "memory");
            else                 asm volatile("s_waitcnt vmcnt(4)" ::: "memory");
        } else {
            asm volatile("s_waitcnt vmcnt(0)" ::: "memory");
        }
        raw_barrier();
        const short* base = s0 + cur * BUF;
        const int abase = lg * 1024 + (wr * 64 + lr) * 8;
        const int bbase = 4096 + lg * 1024 + (wc * 64 + lr) * 8;
        v8s ah[4], bh[4];
#pragma unroll
        for (int q = 0; q < 4; ++q) {
            ah[q] = *(const v8s*)(base + abase + q * 128);
            bh[q] = *(const v8s*)(base + bbase + q * 128);
        }
        if constexpr (SPLIT) {
            v8s al[4], bl[4];
#pragma unroll
            for (int q = 0; q < 4; ++q) {
                al[q] = *(const v8s*)(base + 8192 + abase + q * 128);
                bl[q] = *(const v8s*)(base + 8192 + bbase + q * 128);
            }
#pragma unroll
            for (int mi = 0; mi < 4; ++mi)
#pragma unroll
                for (int nj = 0; nj < 4; ++nj) {
                    acc[mi][nj] = __builtin_amdgcn_mfma_f32_16x16x32_bf16(ah[mi], bh[nj], acc[mi][nj], 0, 0, 0);
                    acc[mi][nj] = __builtin_amdgcn_mfma_f32_16x16x32_bf16(al[mi], bh[nj], acc[mi][nj], 0, 0, 0);
                    acc[mi][nj] = __builtin_amdgcn_mfma_f32_16x16x32_bf16(ah[mi], bl[nj], acc[mi][nj], 0, 0, 0);
                }
        } else {
#pragma unroll
            for (int mi = 0; mi < 4; ++mi)
#pragma unroll
                for (int nj = 0; nj < 4; ++nj)
                    acc[mi][nj] = __builtin_amdgcn_mfma_f32_16x16x32_bf16(ah[mi], bh[nj], acc[mi][nj], 0, 0, 0);
        }
    }

#pragma unroll
    for (int mi = 0; mi < 4; ++mi) {
        const int mrow = mt * 128 + wr * 64 + mi * 16 + lg * 4;
#pragma unroll
        for (int nj = 0; nj < 4; ++nj) {
            const int ncol = nt * 128 + wc * 64 + nj * 16 + lr;
            if (ncol < p.N) {
#pragma unroll
                for (int rr = 0; rr < 4; ++rr) {
                    const int m = mrow + rr;
                    if (m < Mz) {
                        float v = acc[mi][nj][rr] * p.alpha;
                        long crow;
                        if (p.grouped == 1)      crow = p.ppd[z] + m;
                        else if (p.grouped == 2) crow = p.lrow[z * 2048 + m];
                        else                     crow = m;
                        long co = (long)z * p.strideCz + crow * (long)p.ldc + ncol;
                        if (p.outMode == 0) p.C[co] = v;
                        else                p.C[co] += v;
                    }
                }
            }
        }
    }
}

// ======== BM=256 / BN=128, 512 threads (8 waves: 4M x 2N), 2-deep pipeline ========
template<bool SPLIT>
__global__ __launch_bounds__(512) void gemm_bt256(GemmP p) {
    const int lid = blockIdx.x;
    const int xcd = lid & 7, sI = lid >> 3;
    const int gi = xcd + 8 * (sI / p.S);
    if (gi >= p.G) return;
    const int mt = sI % p.S;
    const int nt = gi % p.ntiles;
    const int z  = gi / p.ntiles;
    if (p.causalSkip && nt > 2 * mt + 1) return;

    const int tid = threadIdx.x;
    int Mz = p.grouped ? p.cnt[z] : p.M;
    if (mt * 256 >= Mz) return;

    long bOff;
    if (p.gqaB) { int b = z >> 4, h = z & 15; bOff = (long)(b * 4 + (h >> 2)) * p.strideBz; }
    else bOff = (long)z * p.strideBz;

    extern __shared__ short s0[];
    // per buffer (shorts): A[8192] B[4096] (Al[8192] Bl[4096])
    const int BUF = SPLIT ? 24576 : 12288;

    const int lane = tid & 63, w = tid >> 6;      // w 0..7
    const int lr = lane & 15, lg = lane >> 4;
    const int wr = w >> 1, wc = w & 1;            // wr 0..3, wc 0..1

    v4f acc[4][4];
#pragma unroll
    for (int i = 0; i < 4; ++i)
#pragma unroll
        for (int j = 0; j < 4; ++j) { acc[i][j][0] = 0.f; acc[i][j][1] = 0.f; acc[i][j][2] = 0.f; acc[i][j][3] = 0.f; }

    // B staging: 8 units of 512 shorts; wave w stages unit w
    const short* bks  = p.Bh + bOff + (long)nt * 128 * p.K + (long)w * 512 + lane * 8;
    const short* bksL = SPLIT ? p.Bl + bOff + (long)nt * 128 * p.K + (long)w * 512 + lane * 8 : nullptr;
    // A staging: 16 units across 2 panels; wave w stages units 2w, 2w+1
    const long aPanelBase = (p.grouped ? (long)(p.ppd[z] >> 7) : (long)z * p.aPanelsZ) + 2L * mt;
    const int u0 = 2 * w, u1 = 2 * w + 1;
    const short* aks0  = p.Ah + (aPanelBase + (u0 >> 3)) * 128L * p.K + (long)(u0 & 7) * 512 + lane * 8;
    const short* aks1  = p.Ah + (aPanelBase + (u1 >> 3)) * 128L * p.K + (long)(u1 & 7) * 512 + lane * 8;
    const short* aks0L = SPLIT ? p.Al + (aPanelBase + (u0 >> 3)) * 128L * p.K + (long)(u0 & 7) * 512 + lane * 8 : nullptr;
    const short* aks1L = SPLIT ? p.Al + (aPanelBase + (u1 >> 3)) * 128L * p.K + (long)(u1 & 7) * 512 + lane * 8 : nullptr;
    short* dA0 = s0 + u0 * 512;
    short* dA1 = s0 + u1 * 512;
    short* dB  = s0 + 8192 + w * 512;

    const int nIter = p.K >> 5;
    {
        gload16(aks0, dA0);
        gload16(aks1, dA1);
        gload16(bks,  dB);
        if (SPLIT) {
            gload16(aks0L, dA0 + 12288);
            gload16(aks1L, dA1 + 12288);
            gload16(bksL,  dB + 12288);
        }
    }
    for (int i = 0; i < nIter; ++i) {
        const int cur = i & 1;
        if (i + 1 < nIter) {
            raw_barrier();
            const long kb = (long)(i + 1) * 4096;
            const int boff = (cur ^ 1) * BUF;
            gload16(aks0 + kb, dA0 + boff);
            gload16(aks1 + kb, dA1 + boff);
            gload16(bks + kb,  dB + boff);
            if (SPLIT) {
                gload16(aks0L + kb, dA0 + boff + 12288);
                gload16(aks1L + kb, dA1 + boff + 12288);
                gload16(bksL + kb,  dB + boff + 12288);
            }
            if constexpr (SPLIT) asm volatile("s_waitcnt vmcnt(6)" ::: "memory");
            else                 asm volatile("s_waitcnt vmcnt(3)" ::: "memory");
        } else {
            asm volatile("s_waitcnt vmcnt(0)" ::: "memory");
        }
        raw_barrier();
        const short* base = s0 + cur * BUF;
        const int abase = (wr >> 1) * 4096 + lg * 1024 + ((wr & 1) * 64 + lr) * 8;
        const int bbase = 8192 + lg * 1024 + (wc * 64 + lr) * 8;
        v8s ah[4], bh[4];
#pragma unroll
        for (int q = 0; q < 4; ++q) {
            ah[q] = *(const v8s*)(base + abase + q * 128);
            bh[q] = *(const v8s*)(base + bbase + q * 128);
        }
        if constexpr (SPLIT) {
            v8s al[4], bl[4];
#pragma unroll
            for (int q = 0; q < 4; ++q) {
                al[q] = *(const v8s*)(base + 12288 + abase + q * 128);
                bl[q] = *(const v8s*)(base + 12288 + bbase + q * 128);
            }
#pragma unroll
            for (int mi = 0; mi < 4; ++mi)
#pragma unroll
                for (int nj = 0; nj < 4; ++nj) {
                    acc[mi][nj] = __builtin_amdgcn_mfma_f32_16x16x32_bf16(ah[mi], bh[nj], acc[mi][nj], 0, 0, 0);
                    acc[mi][nj] = __builtin_amdgcn_mfma_f32_16x16x32_bf16(al[mi], bh[nj], acc[mi][nj], 0, 0, 0);
                    acc[mi][nj] = __builtin_amdgcn_mfma_f32_16x16x32_bf16(ah[mi], bl[nj], acc[mi][nj], 0, 0, 0);
                }
        } else {
#pragma unroll
            for (int mi = 0; mi < 4; ++mi)
#pragma unroll
                for (int nj = 0; nj < 4; ++nj)
                    acc[mi][nj] = __builtin_amdgcn_mfma_f32_16x16x32_bf16(ah[mi], bh[nj], acc[mi][nj], 0, 0, 0);
        }
    }

#pragma unroll
    for (int mi = 0; mi < 4; ++mi) {
        const int mrow = mt * 256 + wr * 64 + mi * 16 + lg * 4;
#pragma unroll
        for (int nj = 0; nj < 4; ++nj) {
            const int ncol = nt * 128 + wc * 64 + nj * 16 + lr;
            if (ncol < p.N) {
#pragma unroll
                for (int rr = 0; rr < 4; ++rr) {
                    const int m = mrow + rr;
                    if (m < Mz) {
                        float v = acc[mi][nj][rr] * p.alpha;
                        long crow;
                        if (p.grouped == 1)      crow = p.ppd[z] + m;
                        else if (p.grouped == 2) crow = p.lrow[z * 2048 + m];
                        else                     crow = m;
                        long co = (long)z * p.strideCz + crow * (long)p.ldc + ncol;
                        if (p.outMode == 0) p.C[co] = v;
                        else                p.C[co] += v;
                    }
                }
            }
        }
    }
}

// ======== PV kernel: A = P row-major hi|lo (reg-staged), B = V^T tiled; TILED split out ========
__global__ __launch_bounds__(256) void gemm_pv(GemmP p) {
    const int lid = blockIdx.x;
    const int xcd = lid & 7, sI = lid >> 3;
    const int gi = xcd + 8 * (sI / p.S);
    if (gi >= p.G) return;
    const int mt = sI % p.S;
    const int z  = gi;                      // ntiles = 1
    const int tid = threadIdx.x;

    const int b = z >> 4, h = z & 15;
    const long bOff = (long)(b * 4 + (h >> 2)) * p.strideBz;

    extern __shared__ short s0[];
    short* Ahs = s0;
    short* Bhs = s0 + 4096;
    short* Als = s0 + 8192;
    short* Bls = s0 + 12288;

    const int lane = tid & 63, w = tid >> 6;
    const int lr = lane & 15, lg = lane >> 4;
    const int wr = w >> 1, wc = w & 1;

    v4f acc[4][4];
#pragma unroll
    for (int i = 0; i < 4; ++i)
#pragma unroll
        for (int j = 0; j < 4; ++j) { acc[i][j][0] = 0.f; acc[i][j][1] = 0.f; acc[i][j][2] = 0.f; acc[i][j][3] = 0.f; }

    const short* bks  = p.Bh + bOff + (long)w * 1024 + lane * 8;
    const short* bksL = p.Bl + bOff + (long)w * 1024 + lane * 8;

    const int r = tid & 127;
    const int kgA = tid >> 7;
    const int am = mt * 128 + r;
    const long arowoff = (long)z * p.strideAz + (long)am * p.lda;
    const short* aH = p.Ah + arowoff + kgA * 16;
    const short* aL = p.Al + arowoff + kgA * 16;
    short* sA0 = s0 + (kgA * 256 + r) * 8; short* sA1 = sA0 + 1024;
    short* sA0l = s0 + 8192 + (kgA * 256 + r) * 8; short* sA1l = sA0l + 1024;

    const int kEnd = min(p.K, (mt + 1) * 128);
    const int wb = w * 1024;
    for (int k0 = 0; k0 < kEnd; k0 += 32) {
        const long kb = (long)k0 * 128;
        uint4 a0 = *(const uint4*)(aH + k0);
        uint4 a1 = *(const uint4*)(aH + k0 + 8);
        uint4 a0l = *(const uint4*)(aL + k0);
        uint4 a1l = *(const uint4*)(aL + k0 + 8);
        __syncthreads();
        gload16(bks + kb,       Bhs + wb);
        gload16(bks + kb + 512, Bhs + wb + 512);
        gload16(bksL + kb,       Bls + wb);
        gload16(bksL + kb + 512, Bls + wb + 512);
        *(uint4*)sA0 = a0; *(uint4*)sA1 = a1;
        *(uint4*)sA0l = a0l; *(uint4*)sA1l = a1l;
        __syncthreads();
        const int abase = lg * 1024 + (wr * 64 + lr) * 8;
        const int bbase = lg * 1024 + (wc * 64 + lr) * 8;
        v8s ah[4], bh[4], al[4], bl[4];
#pragma unroll
        for (int q = 0; q < 4; ++q) {
            ah[q] = *(const v8s*)(Ahs + abase + q * 128);
            bh[q] = *(const v8s*)(Bhs + bbase + q * 128);
            al[q] = *(const v8s*)(Als + abase + q * 128);
            bl[q] = *(const v8s*)(Bls + bbase + q * 128);
        }
#pragma unroll
        for (int mi = 0; mi < 4; ++mi)
#pragma unroll
            for (int nj = 0; nj < 4; ++nj) {
                acc[mi][nj] = __builtin_amdgcn_mfma_f32_16x16x32_bf16(ah[mi], bh[nj], acc[mi][nj], 0, 0, 0);
                acc[mi][nj] = __builtin_amdgcn_mfma_f32_16x16x32_bf16(al[mi], bh[nj], acc[mi][nj], 0, 0, 0);
                acc[mi][nj] = __builtin_amdgcn_mfma_f32_16x16x32_bf16(ah[mi], bl[nj], acc[mi][nj], 0, 0, 0);
            }
    }

#pragma unroll
    for (int mi = 0; mi < 4; ++mi) {
        const int mrow = mt * 128 + wr * 64 + mi * 16 + lg * 4;
#pragma unroll
        for (int nj = 0; nj < 4; ++nj) {
            const int ncol = wc * 64 + nj * 16 + lr;
            if (ncol < 64) {
#pragma unroll
                for (int rr = 0; rr < 4; ++rr) {
                    const int m = mrow + rr;
                    float v = acc[mi][nj][rr];
                    int grow = b * 1024 + m, col = h * 64 + ncol;
                    long dst = ((long)(grow >> 7)) * 131072 + ((long)(col >> 5) << 12)
                             + ((long)((col >> 3) & 3) << 10) + ((long)(grow & 127) << 3) + (col & 7);
                    short hi = f2bf(v);
                    p.Ch[dst] = hi;
                    p.Cl[dst] = f2bf(v - bf2f(hi));
                }
            }
        }
    }
}

// ---------------- small kernels ----------------
__global__ __launch_bounds__(256) void embed_kernel(const int* toks, const float* emb, float* X) {
    const int t = blockIdx.x;
    const int tok = toks[t];
    const float4* s = (const float4*)(emb + (size_t)tok * 1024);
    float4* d = (float4*)(X + (size_t)t * 1024);
    d[threadIdx.x] = s[threadIdx.x];
}

__global__ __launch_bounds__(256) void rmsnorm_split(const float* X, const float* w, short* oh, short* ol) {
    __shared__ float red[4];
    const long t = blockIdx.x;
    const float* r = X + t * 1024;
    float ss = 0.f;
    for (int j = threadIdx.x; j < 1024; j += 256) { float f = r[j]; ss += f * f; }
    ss = block_sum256(ss, red);
    const float sc = 32.f / fmaxf(sqrtf(ss), 1e-6f);
    if (threadIdx.x < 128) {
        const int g = threadIdx.x, f = g * 8;
        float v[8];
#pragma unroll
        for (int j = 0; j < 8; ++j) v[j] = r[f + j] * sc * w[f + j];
        long dst = (t >> 7) * 131072 + ((long)(g >> 2) << 12) + ((long)(g & 3) << 10) + ((t & 127) << 3);
        short h[8], lo[8];
#pragma unroll
        for (int j = 0; j < 8; ++j) { h[j] = f2bf(v[j]); lo[j] = f2bf(v[j] - bf2f(h[j])); }
        *(ushort4*)(oh + dst)     = make_ushort4((unsigned short)h[0], (unsigned short)h[1], (unsigned short)h[2], (unsigned short)h[3]);
        *(ushort4*)(oh + dst + 4) = make_ushort4((unsigned short)h[4], (unsigned short)h[5], (unsigned short)h[6], (unsigned short)h[7]);
        *(ushort4*)(ol + dst)     = make_ushort4((unsigned short)lo[0], (unsigned short)lo[1], (unsigned short)lo[2], (unsigned short)lo[3]);
        *(ushort4*)(ol + dst + 4) = make_ushort4((unsigned short)lo[4], (unsigned short)lo[5], (unsigned short)lo[6], (unsigned short)lo[7]);
    }
}

struct RopeF { float f[32]; };

__global__ __launch_bounds__(256) void rope_q_kernel(const float* QKV, short* OH, short* OL, RopeF rf) {
    const int idx = blockIdx.x * 256 + threadIdx.x;
    const int pp = idx & 31, h = (idx >> 5) & 15, s = (idx >> 9) & 1023, b = idx >> 19;
    const float* src = QKV + ((size_t)(b * 1024 + s)) * 1536 + h * 64 + 2 * pp;
    const float x0 = src[0], x1 = src[1];
    const float ang = (float)s * rf.f[pp];
    float sn, cs; sincosf(ang, &sn, &cs);
    const float o0 = x0 * cs - x1 * sn, o1 = x0 * sn + x1 * cs;
    const int z = b * 16 + h, d = 2 * pp;
    const long off = (long)z * 65536 + (long)(s >> 7) * 8192
                   + ((long)(d >> 5) << 12) + ((long)((d >> 3) & 3) << 10)
                   + ((long)(s & 127) << 3) + (d & 7);
    short h0 = f2bf(o0); OH[off] = h0; OL[off] = f2bf(o0 - bf2f(h0));
    short h1 = f2bf(o1); OH[off + 1] = h1; OL[off + 1] = f2bf(o1 - bf2f(h1));
}

__global__ __launch_bounds__(256) void rope_k_kernel(const float* QKV, short* KH, short* KL, RopeF rf) {
    const int idx = blockIdx.x * 256 + threadIdx.x;
    const int pp = idx & 31, kv = (idx >> 5) & 3, s = (idx >> 7) & 1023, b = idx >> 17;
    const float* src = QKV + ((size_t)(b * 1024 + s)) * 1536 + 1024 + kv * 64 + 2 * pp;
    const float x0 = src[0], x1 = src[1];
    const float ang = (float)s * rf.f[pp];
    float sn, cs; sincosf(ang, &sn, &cs);
    const float o0 = x0 * cs - x1 * sn, o1 = x0 * sn + x1 * cs;
    const int z = b * 4 + kv, d = 2 * pp;
    const long off = (long)z * 65536 + (long)(s >> 7) * 8192
                   + ((long)(d >> 5) << 12) + ((long)((d >> 3) & 3) << 10)
                   + ((long)(s & 127) << 3) + (d & 7);
    short h0 = f2bf(o0); KH[off] = h0; KL[off] = f2bf(o0 - bf2f(h0));
    short h1 = f2bf(o1); KH[off + 1] = h1; KL[off + 1] = f2bf(o1 - bf2f(h1));
}

__global__ __launch_bounds__(256) void transpose_v_kernel(const float* QKV, short* VH, short* VL) {
    const int idx = blockIdx.x * 256 + threadIdx.x;
    const int d = idx & 63, kv = (idx >> 6) & 3, s = (idx >> 8) & 1023, b = idx >> 18;
    const float f = QKV[((size_t)(b * 1024 + s)) * 1536 + 1280 + kv * 64 + d];
    const int z = b * 4 + kv;
    const long off = (long)z * 131072 + ((long)(s >> 5) << 12) + ((long)((s >> 3) & 3) << 10)
                   + ((long)d << 3) + (s & 7);
    short hi = f2bf(f);
    VH[off] = hi; VL[off] = f2bf(f - bf2f(hi));
    VH[off + 512] = 0; VL[off + 512] = 0;
}

__global__ __launch_bounds__(256) void attn_softmax(float* SC) {
    const long row = blockIdx.x;
    const int i = (int)(row & 1023);
    float* r = SC + row * 1024;
    __shared__ float buf[1024];
    __shared__ float red[4];
    const int n = i + 1;
    for (int j = threadIdx.x; j < n; j += 256) buf[j] = r[j];
    __syncthreads();
    float m = -INFINITY;
    for (int j = threadIdx.x; j < n; j += 256) m = fmaxf(m, buf[j]);
    m = block_max256(m, red);
    float s = 0.f;
    for (int j = threadIdx.x; j < n; j += 256) { float e = expf(buf[j] - m); buf[j] = e; s += e; }
    s = block_sum256(s, red);
    const float inv = 1.f / s;
    short* rh = (short*)r;
    short* rl = rh + 1024;
    __syncthreads();
    for (int j = threadIdx.x; j < 1024; j += 256) {
        float pv = (j < n) ? buf[j] * inv : 0.f;
        short hi = f2bf(pv);
        rh[j] = hi;
        rl[j] = f2bf(pv - bf2f(hi));
    }
}

__global__ __launch_bounds__(256) void router_kernel(const float* X, const float* wn, const float* rw,
                                                     float* probs, float* lse, int* cnt, int* ltok, int* lrow) {
    __shared__ float xs[1024];
    __shared__ float red[4];
    __shared__ float lg[8];
    const int t = blockIdx.x;
    const float* r = X + (size_t)t * 1024;
    for (int j = threadIdx.x; j < 1024; j += 256) xs[j] = r[j];
    __syncthreads();
    float ss = 0.f;
    for (int j = threadIdx.x; j < 1024; j += 256) ss += xs[j] * xs[j];
    ss = block_sum256(ss, red);
    const float sc = 32.f / fmaxf(sqrtf(ss), 1e-6f);
    float acc[8] = {0, 0, 0, 0, 0, 0, 0, 0};
    for (int j = threadIdx.x; j < 1024; j += 256) {
        const float xv = xs[j] * wn[j];
#pragma unroll
        for (int e = 0; e < 8; ++e) acc[e] += xv * rw[e * 1024 + j];
    }
#pragma unroll
    for (int e = 0; e < 8; ++e) {
        float s = block_sum256(acc[e], red);
        if (threadIdx.x == 0) lg[e] = s * sc;
    }
    __syncthreads();
    if (threadIdx.x == 0) {
        float m = lg[0];
        for (int e = 1; e < 8; ++e) m = fmaxf(m, lg[e]);
        float ex[8], se = 0.f;
        for (int e = 0; e < 8; ++e) { ex[e] = expf(lg[e] - m); se += ex[e]; }
        const float inv = 1.f / se;
        float pr[8];
        for (int e = 0; e < 8; ++e) { pr[e] = ex[e] * inv; probs[(size_t)t * 8 + e] = pr[e]; }
        lse[t] = m + logf(se);
        int i1 = 0;
        for (int e = 1; e < 8; ++e) if (pr[e] > pr[i1]) i1 = e;
        int i2 = (i1 == 0) ? 1 : 0;
        for (int e = 0; e < 8; ++e) if (e != i1 && pr[e] > pr[i2]) i2 = e;
        int s1 = atomicAdd(&cnt[i1], 1); ltok[i1 * 2048 + s1] = t; lrow[i1 * 2048 + s1] = 2 * t;
        int s2 = atomicAdd(&cnt[i2], 1); ltok[i2 * 2048 + s2] = t; lrow[i2 * 2048 + s2] = 2 * t + 1;
    }
}

__global__ void prefix_kernel(const int* cnt, int* ppd) {
    if (threadIdx.x == 0 && blockIdx.x == 0) {
        int a = 0;
        for (int e = 0; e < 8; ++e) { ppd[e] = a; a += ((cnt[e] + 255) >> 8) << 8; }
    }
}

__global__ __launch_bounds__(256) void gather_kernel(const short* XNH, const short* XNL,
                                                     const int* cnt, const int* ppd, const int* ltok,
                                                     short* GXNH, short* GXNL) {
    const int e = blockIdx.y, i = blockIdx.x;
    if (i >= cnt[e]) return;
    const int t = ltok[e * 2048 + i];
    const int pd = ppd[e] + i;
    const int plane = threadIdx.x >> 7, g = threadIdx.x & 127;
    const long goff = ((long)(g >> 2) << 12) + ((long)(g & 3) << 10);
    const long src = (long)(t >> 7) * 131072 + goff + ((t & 127) << 3);
    const long dst = (long)(pd >> 7) * 131072 + goff + ((pd & 127) << 3);
    const short* S = plane ? XNL : XNH;
    short* D = plane ? GXNL : GXNH;
    *(uint4*)(D + dst) = *(const uint4*)(S + src);
}

// silu over padded U rows [6144][4096] -> tiled split H (K=2048)
__global__ __launch_bounds__(256) void silu_mul(const float* U, short* HH, short* HL) {
    const int row = blockIdx.x, g = threadIdx.x;
    const float* ur = U + (long)row * 4096 + g * 8;
    const float4 u0 = *(const float4*)ur, u1 = *(const float4*)(ur + 4);
    const float4 g0 = *(const float4*)(ur + 2048), g1 = *(const float4*)(ur + 2052);
    float h[8];
    h[0] = (u0.x / (1.f + expf(-u0.x))) * g0.x;
    h[1] = (u0.y / (1.f + expf(-u0.y))) * g0.y;
    h[2] = (u0.z / (1.f + expf(-u0.z))) * g0.z;
    h[3] = (u0.w / (1.f + expf(-u0.w))) * g0.w;
    h[4] = (u1.x / (1.f + expf(-u1.x))) * g1.x;
    h[5] = (u1.y / (1.f + expf(-u1.y))) * g1.y;
    h[6] = (u1.z / (1.f + expf(-u1.z))) * g1.z;
    h[7] = (u1.w / (1.f + expf(-u1.w))) * g1.w;
    const long dst = (long)(row >> 7) * 262144 + ((long)(g >> 2) << 12) + ((long)(g & 3) << 10) + ((row & 127) << 3);
    short hh[8], ll[8];
#pragma unroll
    for (int j = 0; j < 8; ++j) { hh[j] = f2bf(h[j]); ll[j] = f2bf(h[j] - bf2f(hh[j])); }
    *(ushort4*)(HH + dst)     = make_ushort4((unsigned short)hh[0], (unsigned short)hh[1], (unsigned short)hh[2], (unsigned short)hh[3]);
    *(ushort4*)(HH + dst + 4) = make_ushort4((unsigned short)hh[4], (unsigned short)hh[5], (unsigned short)hh[6], (unsigned short)hh[7]);
    *(ushort4*)(HL + dst)     = make_ushort4((unsigned short)ll[0], (unsigned short)ll[1], (unsigned short)ll[2], (unsigned short)ll[3]);
    *(ushort4*)(HL + dst + 4) = make_ushort4((unsigned short)ll[4], (unsigned short)ll[5], (unsigned short)ll[6], (unsigned short)ll[7]);
}

__global__ __launch_bounds__(256) void combine_kernel(float* X, const float* Y) {
    const int i4 = blockIdx.x * 256 + threadIdx.x;
    const int t = i4 >> 8, d4 = i4 & 255;
    float4 x = ((float4*)X)[i4];
    const float4 a = ((const float4*)Y)[(size_t)(2 * t) * 256 + d4];
    const float4 b = ((const float4*)Y)[(size_t)(2 * t + 1) * 256 + d4];
    x.x += a.x + b.x; x.y += a.y + b.y; x.z += a.z + b.z; x.w += a.w + b.w;
    ((float4*)X)[i4] = x;
}

__global__ __launch_bounds__(256) void aux_kernel(const float* probs, const float* lse, float* auxb, int layer) {
    __shared__ float red[4];
    float sl = 0.f;
    for (int t = threadIdx.x; t < 2048; t += 256) sl += lse[t];
    sl = block_sum256(sl, red);
    float s1 = 0.f, s2 = 0.f;
    for (int i = threadIdx.x; i < 8192; i += 256) {
        const float l = probs[i] + probs[8192 + i];
        s1 += l; s2 += l * l;
    }
    s1 = block_sum256(s1, red);
    s2 = block_sum256(s2, red);
    if (threadIdx.x == 0) {
        const float ml = sl / 2048.f;
        const float mean = s1 / 8192.f;
        const float var = fmaxf((s2 - s1 * s1 / 8192.f) / 8191.f, 0.f);
        auxb[layer] = 0.001f * (ml * ml + var / (mean * mean));
    }
}

__global__ void finalize_aux(const float* auxb, float* out) {
    if (threadIdx.x == 0 && blockIdx.x == 0)
        out[(size_t)2 * 1024 * 32000] = auxb[0] + auxb[1];
}

// ---------------- launch helpers ----------------
static void run_gemm128(hipStream_t s, bool split, GemmP& p, int ntiles, int mtiles, int zdim) {
    p.ntiles = ntiles; p.S = mtiles;
    p.G = ntiles * zdim;
    int Gp = (p.G + 7) & ~7;
    long nb = (long)Gp * mtiles;
    dim3 g((unsigned)nb, 1, 1), b(256);
    if (split) gemm_bt128<true><<<g, b, 65536, s>>>(p);
    else       gemm_bt128<false><<<g, b, 32768, s>>>(p);
}

static void run_gemm256(hipStream_t s, bool split, GemmP& p, int ntiles, int mtiles, int zdim) {
    p.ntiles = ntiles; p.S = mtiles;
    p.G = ntiles * zdim;
    int Gp = (p.G + 7) & ~7;
    long nb = (long)Gp * mtiles;
    dim3 g((unsigned)nb, 1, 1), b(512);
    if (split) gemm_bt256<true><<<g, b, 98304, s>>>(p);
    else       gemm_bt256<false><<<g, b, 49152, s>>>(p);
}

static void run_tile(hipStream_t s, const float* src, short* hi, short* lo,
                     long rows, int K, long chunkRows, long chunkPanelStride) {
    long groups = rows * (K / 8);
    long nb = (groups + 255) / 256; if (nb > 2048) nb = 2048;
    conv_tile<<<(unsigned)nb, 256, 0, s>>>(src, hi, lo, groups, K / 8, chunkRows, chunkPanelStride);
}

extern "C" void kernel_launch(void* const* d_in, const int* in_sizes, int n_in,
                              void* d_out, int out_size, void* d_ws, size_t ws_size,
                              hipStream_t stream) {
    (void)in_sizes; (void)n_in; (void)out_size; (void)ws_size;
    const int*   tokens = (const int*)d_in[0];
    const float* tok_emb = (const float*)d_in[1];
    const float* norm1 = (const float*)d_in[2];
    const float* norm2 = (const float*)d_in[3];
    const float* wq = (const float*)d_in[4];
    const float* wk = (const float*)d_in[5];
    const float* wv = (const float*)d_in[6];
    const float* wo = (const float*)d_in[7];
    const float* rw = (const float*)d_in[8];
    const float* w1 = (const float*)d_in[9];
    const float* w2 = (const float*)d_in[10];
    const float* w3 = (const float*)d_in[11];
    const float* normf = (const float*)d_in[12];
    const float* headw = (const float*)d_in[13];
    float* out = (float*)d_out;

    char* w = (char*)d_ws;
    const size_t MB = 1024ull * 1024ull;
    float* X    = (float*)(w + 0);            // 8 MB residual fp32
    short* XNH  = (short*)(w + 8 * MB);
    short* XNL  = (short*)(w + 12 * MB);
    short* QRH  = (short*)(w + 16 * MB);      // tiled Q-hat; aliased as AO after QK^T
    short* QRL  = (short*)(w + 20 * MB);
    short* AOH  = QRH;
    short* AOL  = QRL;
    short* KRH  = (short*)(w + 24 * MB);
    short* KRL  = (short*)(w + 25 * MB);
    short* VTH  = (short*)(w + 26 * MB);
    short* VTL  = (short*)(w + 28 * MB);
    // BIG union region 32..216 MB:
    float* QKV  = (float*)(w + 32 * MB);      // 12 MB (attn phase)
    float* SC   = (float*)(w + 32 * MB);      // 128 MB (attn phase)
    short* GXNH = (short*)(w + 32 * MB);      // 12 MB (MoE phase, 6144 rows)
    short* GXNL = (short*)(w + 44 * MB);      // 12 MB
    float* U    = (float*)(w + 56 * MB);      // 96 MB [6144][4096]
    short* HH   = (short*)(w + 152 * MB);     // 24 MB
    short* HL   = (short*)(w + 176 * MB);     // 24 MB
    float* Y    = (float*)(w + 200 * MB);     // 16 MB
    float* PROBS= (float*)(w + 216 * MB);               // 64 KB
    float* LSE  = (float*)(w + 216 * MB + 65536);
    int*   CNT  = (int*)  (w + 216 * MB + 73728);
    int*   PPD  = (int*)  (w + 216 * MB + 73856);
    int*   LTOK = (int*)  (w + 216 * MB + 74240);
    int*   LROW = (int*)  (w + 216 * MB + 74240 + 65536);
    float* AUXB = (float*)(w + 216 * MB + 74240 + 131072);
    // converted weights (all TILED):
    short* WQKVH = (short*)(w + 218 * MB);    // 6 MB
    short* WQKVL = (short*)(w + 224 * MB);    // 6 MB
    short* WOH   = (short*)(w + 230 * MB);    // 4 MB
    short* WOL   = (short*)(w + 234 * MB);    // 4 MB
    short* W12H  = (short*)(w + 238 * MB);    // 64 MB per-layer
    short* W12L  = (short*)(w + 302 * MB);    // 64 MB (layer 0 only; head aliases after)
    short* W3H   = (short*)(w + 366 * MB);    // 32 MB per-layer
    short* W3L   = (short*)(w + 398 * MB);    // 32 MB (layer 0 only)
    short* HDH   = (short*)(w + 302 * MB);    // 62.5 MB, aliases W12L
    // total ~430 MB

    RopeF rf;
    for (int i = 0; i < 32; ++i) {
        float t = (float)pow(10000.0, (double)(2 * i) / 64.0);
        rf.f[i] = 1.0f / t;
    }

    for (int l = 0; l < 2; ++l) {
        long qo = (long)l * 1572864;
        run_tile(stream, wq + (long)l * 1048576, WQKVH + qo,           WQKVL + qo,           1024, 1024, 1024, 8);
        run_tile(stream, wk + (long)l * 262144,  WQKVH + qo + 1048576, WQKVL + qo + 1048576, 256, 1024, 256, 2);
        run_tile(stream, wv + (long)l * 262144,  WQKVH + qo + 1310720, WQKVL + qo + 1310720, 256, 1024, 256, 2);
    }
    run_tile(stream, wo, WOH, WOL, 2048, 1024, 2048, 16);

    embed_kernel<<<2048, 256, 0, stream>>>(tokens, tok_emb, X);

    for (int l = 0; l < 2; ++l) {
        const bool msp = (l == 0);
        run_tile(stream, w1 + (long)l * 16777216, W12H,           msp ? W12L : nullptr,           16384, 1024, 2048, 32);
        run_tile(stream, w2 + (long)l * 16777216, W12H + 2097152, msp ? W12L + 2097152 : nullptr, 16384, 1024, 2048, 32);
        run_tile(stream, w3 + (long)l * 16777216, W3H,            msp ? W3L : nullptr,            8192, 2048, 8192, 64);

        rmsnorm_split<<<2048, 256, 0, stream>>>(X, norm1 + l * 1024, XNH, XNL);

        // fused QKV (BM=128): [2048][1536] fp32
        { GemmP p = {}; p.Ah = XNH; p.Al = XNL; p.Bh = WQKVH + (long)l * 1572864; p.Bl = WQKVL + (long)l * 1572864;
          p.C = QKV; p.M = 2048; p.N = 1536; p.K = 1024; p.aPanelsZ = 16; p.ldc = 1536; p.alpha = 1.f;
          run_gemm128(stream, true, p, 12, 16, 1); }

        rope_q_kernel<<<4096, 256, 0, stream>>>(QKV, QRH, QRL, rf);
        rope_k_kernel<<<1024, 256, 0, stream>>>(QKV, KRH, KRL, rf);
        transpose_v_kernel<<<2048, 256, 0, stream>>>(QKV, VTH, VTL);

        // scores = q k^T / 8 (BM=256, causal skip nt>2mt+1)
        { GemmP p = {}; p.Ah = QRH; p.Al = QRL; p.Bh = KRH; p.Bl = KRL; p.C = SC;
          p.M = 1024; p.N = 1024; p.K = 64; p.aPanelsZ = 8; p.ldc = 1024;
          p.strideBz = 65536; p.strideCz = 1048576;
          p.alpha = 0.125f; p.gqaB = 1; p.causalSkip = 1;
          run_gemm256(stream, true, p, 8, 4, 32); }

        attn_softmax<<<32768, 256, 0, stream>>>(SC);

        // PV (dedicated kernel)
        { GemmP p = {}; p.Ah = (short*)SC; p.Al = (short*)SC + 1024; p.Bh = VTH; p.Bl = VTL; p.Ch = AOH; p.Cl = AOL;
          p.M = 1024; p.N = 64; p.K = 1024; p.lda = 2048;
          p.strideAz = 2097152; p.strideBz = 131072;
          p.ntiles = 1; p.S = 8; p.G = 32;
          long nb = 32L * 8;
          gemm_pv<<<dim3((unsigned)nb), dim3(256), 32768, stream>>>(p); }

        // x += 0.5 * attno @ wo^T (BM=128)
        { GemmP p = {}; p.Ah = AOH; p.Al = AOL; p.Bh = WOH + (long)l * 1048576; p.Bl = WOL + (long)l * 1048576; p.C = X;
          p.M = 2048; p.N = 1024; p.K = 1024; p.aPanelsZ = 16; p.ldc = 1024;
          p.alpha = 0.5f; p.outMode = 1;
          run_gemm128(stream, true, p, 8, 16, 1); }

        // ---- MoE ----
        rmsnorm_split<<<2048, 256, 0, stream>>>(X, norm2 + l * 1024, XNH, XNL);
        hipMemsetAsync(CNT, 0, 8 * sizeof(int), stream);
        router_kernel<<<2048, 256, 0, stream>>>(X, norm2 + l * 1024, rw + (size_t)l * 8 * 1024,
                                                PROBS, LSE, CNT, LTOK, LROW);
        prefix_kernel<<<1, 64, 0, stream>>>(CNT, PPD);
        { dim3 gg(2048, 8); gather_kernel<<<gg, 256, 0, stream>>>(XNH, XNL, CNT, PPD, LTOK, GXNH, GXNL); }

        // fused u|g (BM=256)
        { GemmP p = {}; p.Ah = GXNH; p.Al = GXNL; p.Bh = W12H; p.Bl = W12L; p.C = U;
          p.M = 2048; p.N = 4096; p.K = 1024; p.ldc = 4096;
          p.strideBz = 4194304; p.strideCz = 0; p.alpha = 1.f; p.grouped = 1;
          p.cnt = CNT; p.ppd = PPD; p.lrow = LROW;
          run_gemm256(stream, msp, p, 32, 8, 8); }
        silu_mul<<<6144, 256, 0, stream>>>(U, HH, HL);
        // y = h @ w3^T (BM=256), scatter rows by lrow into Y
        { GemmP p = {}; p.Ah = HH; p.Al = HL; p.Bh = W3H; p.Bl = W3L; p.C = Y;
          p.M = 2048; p.N = 1024; p.K = 2048; p.ldc = 1024;
          p.strideBz = 2097152; p.strideCz = 0; p.alpha = 1.f; p.grouped = 2;
          p.cnt = CNT; p.ppd = PPD; p.lrow = LROW;
          run_gemm256(stream, msp, p, 8, 8, 8); }
        combine_kernel<<<2048, 256, 0, stream>>>(X, Y);
        aux_kernel<<<1, 256, 0, stream>>>(PROBS, LSE, AUXB, l);

        if (l == 0)
            run_tile(stream, headw, HDH, nullptr, 32000, 1024, 32000, 250);
    }

    rmsnorm_split<<<2048, 256, 0, stream>>>(X, normf, XNH, XNL);
    { GemmP p = {}; p.Ah = XNH; p.Bh = HDH; p.C = out;
      p.M = 2048; p.N = 32000; p.K = 1024; p.aPanelsZ = 16; p.ldc = 32000; p.alpha = 1.f;
      run_gemm256(stream, false, p, 250, 8, 1); }
    finalize_aux<<<1, 1, 0, stream>>>(AUXB, out);
}

// Round 8
// 2020.072 us; speedup vs baseline: 1.1757x; 1.0711x over previous
//
#include <hip/hip_runtime.h>
#include <math.h>

#define DEV __device__ __forceinline__

using v8s = __attribute__((ext_vector_type(8))) short;   // 8 bf16 (4 VGPRs)
using v4f = __attribute__((ext_vector_type(4))) float;   // 4 fp32 acc

// ---------- bf16 helpers (RNE) ----------
DEV short f2bf(float f) {
    unsigned u = __float_as_uint(f);
    unsigned r = (u + 0x7fffu + ((u >> 16) & 1u)) >> 16;
    return (short)(unsigned short)r;
}
DEV float bf2f(short s) {
    return __uint_as_float(((unsigned)(unsigned short)s) << 16);
}

// async global->LDS: src per-lane (includes lane*8 shorts), dst wave-uniform base; HW adds lane*16B
DEV void gload16(const short* g, short* l) {
    __builtin_amdgcn_global_load_lds((const __attribute__((address_space(1))) void*)g,
                                     (__attribute__((address_space(3))) void*)l,
                                     16, 0, 0);
}

DEV void raw_barrier() { asm volatile("s_barrier" ::: "memory"); }

// ---------- block reductions (256 threads = 4 waves) ----------
DEV float block_sum256(float v, float* red) {
    __syncthreads();
#pragma unroll
    for (int o = 32; o >= 1; o >>= 1) v += __shfl_down(v, o, 64);
    if ((threadIdx.x & 63) == 0) red[threadIdx.x >> 6] = v;
    __syncthreads();
    return red[0] + red[1] + red[2] + red[3];
}
DEV float block_max256(float v, float* red) {
    __syncthreads();
#pragma unroll
    for (int o = 32; o >= 1; o >>= 1) v = fmaxf(v, __shfl_down(v, o, 64));
    if ((threadIdx.x & 63) == 0) red[threadIdx.x >> 6] = v;
    __syncthreads();
    return fmaxf(fmaxf(red[0], red[1]), fmaxf(red[2], red[3]));
}

// ---------------- model constants ----------------
// V=32000 D=1024 L=2 H=16 KVH=4 HD=64 E=8 FF=2048 K=2 B=2 S=1024

// ---------------- weight conversion to TILED layout ----------------
__global__ __launch_bounds__(256) void conv_tile(const float* __restrict__ src,
                                                 short* __restrict__ hi, short* __restrict__ lo,
                                                 long nGroups, int Kg, long chunkRows, long chunkPanelStride) {
    const long panelElems = 128L * Kg * 8;
    for (long idx = (long)blockIdx.x * 256 + threadIdx.x; idx < nGroups; idx += (long)gridDim.x * 256) {
        long rrow = idx / Kg; int g = (int)(idx - rrow * Kg);
        long c = rrow / chunkRows; int ri = (int)(rrow - c * chunkRows);
        long panel = c * chunkPanelStride + (ri >> 7);
        long dst = panel * panelElems + ((long)(g >> 2) << 12) + ((long)(g & 3) << 10) + ((long)(ri & 127) << 3);
        const float4 f0 = ((const float4*)src)[idx * 2];
        const float4 f1 = ((const float4*)src)[idx * 2 + 1];
        short h0 = f2bf(f0.x), h1 = f2bf(f0.y), h2 = f2bf(f0.z), h3 = f2bf(f0.w);
        short h4 = f2bf(f1.x), h5 = f2bf(f1.y), h6 = f2bf(f1.z), h7 = f2bf(f1.w);
        *(ushort4*)(hi + dst)     = make_ushort4((unsigned short)h0, (unsigned short)h1,
                                                 (unsigned short)h2, (unsigned short)h3);
        *(ushort4*)(hi + dst + 4) = make_ushort4((unsigned short)h4, (unsigned short)h5,
                                                 (unsigned short)h6, (unsigned short)h7);
        if (lo) {
            short l0 = f2bf(f0.x - bf2f(h0)), l1 = f2bf(f0.y - bf2f(h1));
            short l2 = f2bf(f0.z - bf2f(h2)), l3 = f2bf(f0.w - bf2f(h3));
            short l4 = f2bf(f1.x - bf2f(h4)), l5 = f2bf(f1.y - bf2f(h5));
            short l6 = f2bf(f1.z - bf2f(h6)), l7 = f2bf(f1.w - bf2f(h7));
            *(ushort4*)(lo + dst)     = make_ushort4((unsigned short)l0, (unsigned short)l1,
                                                     (unsigned short)l2, (unsigned short)l3);
            *(ushort4*)(lo + dst + 4) = make_ushort4((unsigned short)l4, (unsigned short)l5,
                                                     (unsigned short)l6, (unsigned short)l7);
        }
    }
}

// ---------------- GEMM params ----------------
struct GemmP {
    const short* Ah; const short* Al;
    const short* Bh; const short* Bl;
    float* C; short* Ch; short* Cl;
    const int* cnt; const int* ppd; const int* lrow;
    long aPanelsZ;            // A panels(128-row) per z (tiled, non-grouped)
    long strideAz;            // PV: A elems per z
    long strideBz, strideCz;
    int M, N, K, lda, ldc;
    float alpha;
    int outMode;    // 0 store f32, 1 C += alpha*acc
    int gqaB;       // B z-offset uses GQA mapping
    int grouped;    // 0 none; 1: A panels at ppd[z]>>7, C row = ppd[z]+m; 2: A same, C row = lrow[z*2048+m]
    int causalSkip;
    int ntiles, G, Gx;   // group=(nt,z); Gx=ceil(G/8); member mt is OUTER lid index
};

// ======== BM=128 / BN=128, 256 threads, 2-deep pipeline ========
template<bool SPLIT>
__global__ __launch_bounds__(256) void gemm_bt128(GemmP p) {
    const int lid = blockIdx.x;
    const int xcd = lid & 7, sI = lid >> 3;
    const int gx = sI % p.Gx;          // mt OUTER: active (low-mt) blocks = contiguous lid prefix
    const int mt = sI / p.Gx;
    const int gi = xcd + 8 * gx;
    if (gi >= p.G) return;
    const int nt = gi % p.ntiles;
    const int z  = gi / p.ntiles;
    if (p.causalSkip && nt > mt) return;

    const int tid = threadIdx.x;
    int Mz = p.grouped ? p.cnt[z] : p.M;
    if (mt * 128 >= Mz) return;

    long bOff;
    if (p.gqaB) { int b = z >> 4, h = z & 15; bOff = (long)(b * 4 + (h >> 2)) * p.strideBz; }
    else bOff = (long)z * p.strideBz;

    extern __shared__ short s0[];
    const int BUF = SPLIT ? 16384 : 8192;

    const int lane = tid & 63, w = tid >> 6;
    const int lr = lane & 15, lg = lane >> 4;
    const int wr = w >> 1, wc = w & 1;

    v4f acc[4][4];
#pragma unroll
    for (int i = 0; i < 4; ++i)
#pragma unroll
        for (int j = 0; j < 4; ++j) { acc[i][j][0] = 0.f; acc[i][j][1] = 0.f; acc[i][j][2] = 0.f; acc[i][j][3] = 0.f; }

    const short* bks  = p.Bh + bOff + (long)nt * 128 * p.K + (long)w * 1024 + lane * 8;
    const short* bksL = SPLIT ? p.Bl + bOff + (long)nt * 128 * p.K + (long)w * 1024 + lane * 8 : nullptr;

    long aPanel = (p.grouped ? (long)(p.ppd[z] >> 7) : (long)z * p.aPanelsZ) + mt;
    const short* aks  = p.Ah + aPanel * 128L * p.K + (long)w * 1024 + lane * 8;
    const short* aksL = SPLIT ? p.Al + aPanel * 128L * p.K + (long)w * 1024 + lane * 8 : nullptr;

    const int nIter = p.K >> 5;
    const int wb = w * 1024;
    {
        gload16(aks,       s0 + wb);
        gload16(aks + 512, s0 + wb + 512);
        gload16(bks,       s0 + 4096 + wb);
        gload16(bks + 512, s0 + 4096 + wb + 512);
        if (SPLIT) {
            gload16(aksL,       s0 + 8192 + wb);
            gload16(aksL + 512, s0 + 8192 + wb + 512);
            gload16(bksL,       s0 + 12288 + wb);
            gload16(bksL + 512, s0 + 12288 + wb + 512);
        }
    }
    for (int i = 0; i < nIter; ++i) {
        const int cur = i & 1;
        if (i + 1 < nIter) {
            raw_barrier();
            const long kb = (long)(i + 1) * 4096;
            short* base = s0 + (cur ^ 1) * BUF;
            gload16(aks + kb,       base + wb);
            gload16(aks + kb + 512, base + wb + 512);
            gload16(bks + kb,       base + 4096 + wb);
            gload16(bks + kb + 512, base + 4096 + wb + 512);
            if (SPLIT) {
                gload16(aksL + kb,       base + 8192 + wb);
                gload16(aksL + kb + 512, base + 8192 + wb + 512);
                gload16(bksL + kb,       base + 12288 + wb);
                gload16(bksL + kb + 512, base + 12288 + wb + 512);
            }
            if constexpr (SPLIT) asm volatile("s_waitcnt vmcnt(8)" ::: "memory");
            else                 asm volatile("s_waitcnt vmcnt(4)" ::: "memory");
        } else {
            asm volatile("s_waitcnt vmcnt(0)" ::: "memory");
        }
        raw_barrier();
        const short* base = s0 + cur * BUF;
        const int abase = lg * 1024 + (wr * 64 + lr) * 8;
        const int bbase = 4096 + lg * 1024 + (wc * 64 + lr) * 8;
        v8s ah[4], bh[4];
#pragma unroll
        for (int q = 0; q < 4; ++q) {
            ah[q] = *(const v8s*)(base + abase + q * 128);
            bh[q] = *(const v8s*)(base + bbase + q * 128);
        }
        if constexpr (SPLIT) {
            v8s al[4], bl[4];
#pragma unroll
            for (int q = 0; q < 4; ++q) {
                al[q] = *(const v8s*)(base + 8192 + abase + q * 128);
                bl[q] = *(const v8s*)(base + 8192 + bbase + q * 128);
            }
#pragma unroll
            for (int mi = 0; mi < 4; ++mi)
#pragma unroll
                for (int nj = 0; nj < 4; ++nj) {
                    acc[mi][nj] = __builtin_amdgcn_mfma_f32_16x16x32_bf16(ah[mi], bh[nj], acc[mi][nj], 0, 0, 0);
                    acc[mi][nj] = __builtin_amdgcn_mfma_f32_16x16x32_bf16(al[mi], bh[nj], acc[mi][nj], 0, 0, 0);
                    acc[mi][nj] = __builtin_amdgcn_mfma_f32_16x16x32_bf16(ah[mi], bl[nj], acc[mi][nj], 0, 0, 0);
                }
        } else {
#pragma unroll
            for (int mi = 0; mi < 4; ++mi)
#pragma unroll
                for (int nj = 0; nj < 4; ++nj)
                    acc[mi][nj] = __builtin_amdgcn_mfma_f32_16x16x32_bf16(ah[mi], bh[nj], acc[mi][nj], 0, 0, 0);
        }
    }

#pragma unroll
    for (int mi = 0; mi < 4; ++mi) {
        const int mrow = mt * 128 + wr * 64 + mi * 16 + lg * 4;
#pragma unroll
        for (int nj = 0; nj < 4; ++nj) {
            const int ncol = nt * 128 + wc * 64 + nj * 16 + lr;
            if (ncol < p.N) {
#pragma unroll
                for (int rr = 0; rr < 4; ++rr) {
                    const int m = mrow + rr;
                    if (m < Mz) {
                        float v = acc[mi][nj][rr] * p.alpha;
                        long crow;
                        if (p.grouped == 1)      crow = p.ppd[z] + m;
                        else if (p.grouped == 2) crow = p.lrow[z * 2048 + m];
                        else                     crow = m;
                        long co = (long)z * p.strideCz + crow * (long)p.ldc + ncol;
                        if (p.outMode == 0) p.C[co] = v;
                        else                p.C[co] += v;
                    }
                }
            }
        }
    }
}

// ======== BM=256 / BN=128, 512 threads (8 waves: 4M x 2N), 2-deep pipeline ========
template<bool SPLIT>
__global__ __launch_bounds__(512) void gemm_bt256(GemmP p) {
    const int lid = blockIdx.x;
    const int xcd = lid & 7, sI = lid >> 3;
    const int gx = sI % p.Gx;
    const int mt = sI / p.Gx;
    const int gi = xcd + 8 * gx;
    if (gi >= p.G) return;
    const int nt = gi % p.ntiles;
    const int z  = gi / p.ntiles;
    if (p.causalSkip && nt > 2 * mt + 1) return;

    const int tid = threadIdx.x;
    int Mz = p.grouped ? p.cnt[z] : p.M;
    if (mt * 256 >= Mz) return;

    long bOff;
    if (p.gqaB) { int b = z >> 4, h = z & 15; bOff = (long)(b * 4 + (h >> 2)) * p.strideBz; }
    else bOff = (long)z * p.strideBz;

    extern __shared__ short s0[];
    // per buffer (shorts): A[8192] B[4096] (Al[8192] Bl[4096])
    const int BUF = SPLIT ? 24576 : 12288;

    const int lane = tid & 63, w = tid >> 6;      // w 0..7
    const int lr = lane & 15, lg = lane >> 4;
    const int wr = w >> 1, wc = w & 1;            // wr 0..3, wc 0..1

    v4f acc[4][4];
#pragma unroll
    for (int i = 0; i < 4; ++i)
#pragma unroll
        for (int j = 0; j < 4; ++j) { acc[i][j][0] = 0.f; acc[i][j][1] = 0.f; acc[i][j][2] = 0.f; acc[i][j][3] = 0.f; }

    const short* bks  = p.Bh + bOff + (long)nt * 128 * p.K + (long)w * 512 + lane * 8;
    const short* bksL = SPLIT ? p.Bl + bOff + (long)nt * 128 * p.K + (long)w * 512 + lane * 8 : nullptr;
    const long aPanelBase = (p.grouped ? (long)(p.ppd[z] >> 7) : (long)z * p.aPanelsZ) + 2L * mt;
    const int u0 = 2 * w, u1 = 2 * w + 1;
    const short* aks0  = p.Ah + (aPanelBase + (u0 >> 3)) * 128L * p.K + (long)(u0 & 7) * 512 + lane * 8;
    const short* aks1  = p.Ah + (aPanelBase + (u1 >> 3)) * 128L * p.K + (long)(u1 & 7) * 512 + lane * 8;
    const short* aks0L = SPLIT ? p.Al + (aPanelBase + (u0 >> 3)) * 128L * p.K + (long)(u0 & 7) * 512 + lane * 8 : nullptr;
    const short* aks1L = SPLIT ? p.Al + (aPanelBase + (u1 >> 3)) * 128L * p.K + (long)(u1 & 7) * 512 + lane * 8 : nullptr;
    short* dA0 = s0 + u0 * 512;
    short* dA1 = s0 + u1 * 512;
    short* dB  = s0 + 8192 + w * 512;

    const int nIter = p.K >> 5;
    {
        gload16(aks0, dA0);
        gload16(aks1, dA1);
        gload16(bks,  dB);
        if (SPLIT) {
            gload16(aks0L, dA0 + 12288);
            gload16(aks1L, dA1 + 12288);
            gload16(bksL,  dB + 12288);
        }
    }
    for (int i = 0; i < nIter; ++i) {
        const int cur = i & 1;
        if (i + 1 < nIter) {
            raw_barrier();
            const long kb = (long)(i + 1) * 4096;
            const int boff = (cur ^ 1) * BUF;
            gload16(aks0 + kb, dA0 + boff);
            gload16(aks1 + kb, dA1 + boff);
            gload16(bks + kb,  dB + boff);
            if (SPLIT) {
                gload16(aks0L + kb, dA0 + boff + 12288);
                gload16(aks1L + kb, dA1 + boff + 12288);
                gload16(bksL + kb,  dB + boff + 12288);
            }
            if constexpr (SPLIT) asm volatile("s_waitcnt vmcnt(6)" ::: "memory");
            else                 asm volatile("s_waitcnt vmcnt(3)" ::: "memory");
        } else {
            asm volatile("s_waitcnt vmcnt(0)" ::: "memory");
        }
        raw_barrier();
        const short* base = s0 + cur * BUF;
        const int abase = (wr >> 1) * 4096 + lg * 1024 + ((wr & 1) * 64 + lr) * 8;
        const int bbase = 8192 + lg * 1024 + (wc * 64 + lr) * 8;
        v8s ah[4], bh[4];
#pragma unroll
        for (int q = 0; q < 4; ++q) {
            ah[q] = *(const v8s*)(base + abase + q * 128);
            bh[q] = *(const v8s*)(base + bbase + q * 128);
        }
        if constexpr (SPLIT) {
            v8s al[4], bl[4];
#pragma unroll
            for (int q = 0; q < 4; ++q) {
                al[q] = *(const v8s*)(base + 12288 + abase + q * 128);
                bl[q] = *(const v8s*)(base + 12288 + bbase + q * 128);
            }
#pragma unroll
            for (int mi = 0; mi < 4; ++mi)
#pragma unroll
                for (int nj = 0; nj < 4; ++nj) {
                    acc[mi][nj] = __builtin_amdgcn_mfma_f32_16x16x32_bf16(ah[mi], bh[nj], acc[mi][nj], 0, 0, 0);
                    acc[mi][nj] = __builtin_amdgcn_mfma_f32_16x16x32_bf16(al[mi], bh[nj], acc[mi][nj], 0, 0, 0);
                    acc[mi][nj] = __builtin_amdgcn_mfma_f32_16x16x32_bf16(ah[mi], bl[nj], acc[mi][nj], 0, 0, 0);
                }
        } else {
#pragma unroll
            for (int mi = 0; mi < 4; ++mi)
#pragma unroll
                for (int nj = 0; nj < 4; ++nj)
                    acc[mi][nj] = __builtin_amdgcn_mfma_f32_16x16x32_bf16(ah[mi], bh[nj], acc[mi][nj], 0, 0, 0);
        }
    }

#pragma unroll
    for (int mi = 0; mi < 4; ++mi) {
        const int mrow = mt * 256 + wr * 64 + mi * 16 + lg * 4;
#pragma unroll
        for (int nj = 0; nj < 4; ++nj) {
            const int ncol = nt * 128 + wc * 64 + nj * 16 + lr;
            if (ncol < p.N) {
#pragma unroll
                for (int rr = 0; rr < 4; ++rr) {
                    const int m = mrow + rr;
                    if (m < Mz) {
                        float v = acc[mi][nj][rr] * p.alpha;
                        long crow;
                        if (p.grouped == 1)      crow = p.ppd[z] + m;
                        else if (p.grouped == 2) crow = p.lrow[z * 2048 + m];
                        else                     crow = m;
                        long co = (long)z * p.strideCz + crow * (long)p.ldc + ncol;
                        if (p.outMode == 0) p.C[co] = v;
                        else                p.C[co] += v;
                    }
                }
            }
        }
    }
}

// ======== PV kernel: A = P row-major hi|lo (reg-staged), B = V^T tiled; TILED split out ========
__global__ __launch_bounds__(256) void gemm_pv(GemmP p) {
    const int lid = blockIdx.x;
    const int xcd = lid & 7, sI = lid >> 3;
    const int gx = sI % 4;              // Gx = 32/8 = 4
    const int mt = sI / 4;
    const int z = xcd + 8 * gx;
    const int tid = threadIdx.x;

    const int b = z >> 4, h = z & 15;
    const long bOff = (long)(b * 4 + (h >> 2)) * p.strideBz;

    extern __shared__ short s0[];
    short* Ahs = s0;
    short* Bhs = s0 + 4096;
    short* Als = s0 + 8192;
    short* Bls = s0 + 12288;

    const int lane = tid & 63, w = tid >> 6;
    const int lr = lane & 15, lg = lane >> 4;
    const int wr = w >> 1, wc = w & 1;

    v4f acc[4][4];
#pragma unroll
    for (int i = 0; i < 4; ++i)
#pragma unroll
        for (int j = 0; j < 4; ++j) { acc[i][j][0] = 0.f; acc[i][j][1] = 0.f; acc[i][j][2] = 0.f; acc[i][j][3] = 0.f; }

    const short* bks  = p.Bh + bOff + (long)w * 1024 + lane * 8;
    const short* bksL = p.Bl + bOff + (long)w * 1024 + lane * 8;

    const int r = tid & 127;
    const int kgA = tid >> 7;
    const int am = mt * 128 + r;
    const long arowoff = (long)z * p.strideAz + (long)am * p.lda;
    const short* aH = p.Ah + arowoff + kgA * 16;
    const short* aL = p.Al + arowoff + kgA * 16;
    short* sA0 = s0 + (kgA * 256 + r) * 8; short* sA1 = sA0 + 1024;
    short* sA0l = s0 + 8192 + (kgA * 256 + r) * 8; short* sA1l = sA0l + 1024;

    const int kEnd = min(p.K, (mt + 1) * 128);
    const int wb = w * 1024;
    for (int k0 = 0; k0 < kEnd; k0 += 32) {
        const long kb = (long)k0 * 128;
        uint4 a0 = *(const uint4*)(aH + k0);
        uint4 a1 = *(const uint4*)(aH + k0 + 8);
        uint4 a0l = *(const uint4*)(aL + k0);
        uint4 a1l = *(const uint4*)(aL + k0 + 8);
        __syncthreads();
        gload16(bks + kb,       Bhs + wb);
        gload16(bks + kb + 512, Bhs + wb + 512);
        gload16(bksL + kb,       Bls + wb);
        gload16(bksL + kb + 512, Bls + wb + 512);
        *(uint4*)sA0 = a0; *(uint4*)sA1 = a1;
        *(uint4*)sA0l = a0l; *(uint4*)sA1l = a1l;
        __syncthreads();
        const int abase = lg * 1024 + (wr * 64 + lr) * 8;
        const int bbase = lg * 1024 + (wc * 64 + lr) * 8;
        v8s ah[4], bh[4], al[4], bl[4];
#pragma unroll
        for (int q = 0; q < 4; ++q) {
            ah[q] = *(const v8s*)(Ahs + abase + q * 128);
            bh[q] = *(const v8s*)(Bhs + bbase + q * 128);
            al[q] = *(const v8s*)(Als + abase + q * 128);
            bl[q] = *(const v8s*)(Bls + bbase + q * 128);
        }
#pragma unroll
        for (int mi = 0; mi < 4; ++mi)
#pragma unroll
            for (int nj = 0; nj < 4; ++nj) {
                acc[mi][nj] = __builtin_amdgcn_mfma_f32_16x16x32_bf16(ah[mi], bh[nj], acc[mi][nj], 0, 0, 0);
                acc[mi][nj] = __builtin_amdgcn_mfma_f32_16x16x32_bf16(al[mi], bh[nj], acc[mi][nj], 0, 0, 0);
                acc[mi][nj] = __builtin_amdgcn_mfma_f32_16x16x32_bf16(ah[mi], bl[nj], acc[mi][nj], 0, 0, 0);
            }
    }

#pragma unroll
    for (int mi = 0; mi < 4; ++mi) {
        const int mrow = mt * 128 + wr * 64 + mi * 16 + lg * 4;
#pragma unroll
        for (int nj = 0; nj < 4; ++nj) {
            const int ncol = wc * 64 + nj * 16 + lr;
            if (ncol < 64) {
#pragma unroll
                for (int rr = 0; rr < 4; ++rr) {
                    const int m = mrow + rr;
                    float v = acc[mi][nj][rr];
                    int grow = b * 1024 + m, col = h * 64 + ncol;
                    long dst = ((long)(grow >> 7)) * 131072 + ((long)(col >> 5) << 12)
                             + ((long)((col >> 3) & 3) << 10) + ((long)(grow & 127) << 3) + (col & 7);
                    short hi = f2bf(v);
                    p.Ch[dst] = hi;
                    p.Cl[dst] = f2bf(v - bf2f(hi));
                }
            }
        }
    }
}

// ---------------- small kernels ----------------
__global__ __launch_bounds__(256) void embed_kernel(const int* toks, const float* emb, float* X) {
    const int t = blockIdx.x;
    const int tok = toks[t];
    const float4* s = (const float4*)(emb + (size_t)tok * 1024);
    float4* d = (float4*)(X + (size_t)t * 1024);
    d[threadIdx.x] = s[threadIdx.x];
}

__global__ __launch_bounds__(256) void rmsnorm_split(const float* X, const float* w, short* oh, short* ol) {
    __shared__ float red[4];
    const long t = blockIdx.x;
    const float* r = X + t * 1024;
    float ss = 0.f;
    for (int j = threadIdx.x; j < 1024; j += 256) { float f = r[j]; ss += f * f; }
    ss = block_sum256(ss, red);
    const float sc = 32.f / fmaxf(sqrtf(ss), 1e-6f);
    if (threadIdx.x < 128) {
        const int g = threadIdx.x, f = g * 8;
        float v[8];
#pragma unroll
        for (int j = 0; j < 8; ++j) v[j] = r[f + j] * sc * w[f + j];
        long dst = (t >> 7) * 131072 + ((long)(g >> 2) << 12) + ((long)(g & 3) << 10) + ((t & 127) << 3);
        short h[8], lo[8];
#pragma unroll
        for (int j = 0; j < 8; ++j) { h[j] = f2bf(v[j]); lo[j] = f2bf(v[j] - bf2f(h[j])); }
        *(ushort4*)(oh + dst)     = make_ushort4((unsigned short)h[0], (unsigned short)h[1], (unsigned short)h[2], (unsigned short)h[3]);
        *(ushort4*)(oh + dst + 4) = make_ushort4((unsigned short)h[4], (unsigned short)h[5], (unsigned short)h[6], (unsigned short)h[7]);
        *(ushort4*)(ol + dst)     = make_ushort4((unsigned short)lo[0], (unsigned short)lo[1], (unsigned short)lo[2], (unsigned short)lo[3]);
        *(ushort4*)(ol + dst + 4) = make_ushort4((unsigned short)lo[4], (unsigned short)lo[5], (unsigned short)lo[6], (unsigned short)lo[7]);
    }
}

struct RopeF { float f[32]; };

// fused RoPE-Q / RoPE-K / V-transpose (all write TILED layouts)
__global__ __launch_bounds__(256) void rope_fused_kernel(const float* QKV,
                                                         short* QH, short* QL,
                                                         short* KH, short* KL,
                                                         short* VH, short* VL, RopeF rf) {
    const int bid = blockIdx.x;
    if (bid < 4096) {                                  // Q: B*S*H*32
        const int idx = bid * 256 + threadIdx.x;
        const int pp = idx & 31, h = (idx >> 5) & 15, s = (idx >> 9) & 1023, b = idx >> 19;
        const float* src = QKV + ((size_t)(b * 1024 + s)) * 1536 + h * 64 + 2 * pp;
        const float x0 = src[0], x1 = src[1];
        const float ang = (float)s * rf.f[pp];
        float sn, cs; sincosf(ang, &sn, &cs);
        const float o0 = x0 * cs - x1 * sn, o1 = x0 * sn + x1 * cs;
        const int z = b * 16 + h, d = 2 * pp;
        const long off = (long)z * 65536 + (long)(s >> 7) * 8192
                       + ((long)(d >> 5) << 12) + ((long)((d >> 3) & 3) << 10)
                       + ((long)(s & 127) << 3) + (d & 7);
        short h0 = f2bf(o0); QH[off] = h0; QL[off] = f2bf(o0 - bf2f(h0));
        short h1 = f2bf(o1); QH[off + 1] = h1; QL[off + 1] = f2bf(o1 - bf2f(h1));
    } else if (bid < 5120) {                           // K: B*S*KVH*32
        const int idx = (bid - 4096) * 256 + threadIdx.x;
        const int pp = idx & 31, kv = (idx >> 5) & 3, s = (idx >> 7) & 1023, b = idx >> 17;
        const float* src = QKV + ((size_t)(b * 1024 + s)) * 1536 + 1024 + kv * 64 + 2 * pp;
        const float x0 = src[0], x1 = src[1];
        const float ang = (float)s * rf.f[pp];
        float sn, cs; sincosf(ang, &sn, &cs);
        const float o0 = x0 * cs - x1 * sn, o1 = x0 * sn + x1 * cs;
        const int z = b * 4 + kv, d = 2 * pp;
        const long off = (long)z * 65536 + (long)(s >> 7) * 8192
                       + ((long)(d >> 5) << 12) + ((long)((d >> 3) & 3) << 10)
                       + ((long)(s & 127) << 3) + (d & 7);
        short h0 = f2bf(o0); KH[off] = h0; KL[off] = f2bf(o0 - bf2f(h0));
        short h1 = f2bf(o1); KH[off + 1] = h1; KL[off + 1] = f2bf(o1 - bf2f(h1));
    } else {                                           // V: B*S*KVH*HD
        const int idx = (bid - 5120) * 256 + threadIdx.x;
        const int d = idx & 63, kv = (idx >> 6) & 3, s = (idx >> 8) & 1023, b = idx >> 18;
        const float f = QKV[((size_t)(b * 1024 + s)) * 1536 + 1280 + kv * 64 + d];
        const int z = b * 4 + kv;
        const long off = (long)z * 131072 + ((long)(s >> 5) << 12) + ((long)((s >> 3) & 3) << 10)
                       + ((long)d << 3) + (s & 7);
        short hi = f2bf(f);
        VH[off] = hi; VL[off] = f2bf(f - bf2f(hi));
        VH[off + 512] = 0; VL[off + 512] = 0;
    }
}

__global__ __launch_bounds__(256) void attn_softmax(float* SC) {
    const long row = blockIdx.x;
    const int i = (int)(row & 1023);
    float* r = SC + row * 1024;
    __shared__ float buf[1024];
    __shared__ float red[4];
    const int n = i + 1;
    for (int j = threadIdx.x; j < n; j += 256) buf[j] = r[j];
    __syncthreads();
    float m = -INFINITY;
    for (int j = threadIdx.x; j < n; j += 256) m = fmaxf(m, buf[j]);
    m = block_max256(m, red);
    float s = 0.f;
    for (int j = threadIdx.x; j < n; j += 256) { float e = expf(buf[j] - m); buf[j] = e; s += e; }
    s = block_sum256(s, red);
    const float inv = 1.f / s;
    short* rh = (short*)r;
    short* rl = rh + 1024;
    __syncthreads();
    for (int j = threadIdx.x; j < 1024; j += 256) {
        float pv = (j < n) ? buf[j] * inv : 0.f;
        short hi = f2bf(pv);
        rh[j] = hi;
        rl[j] = f2bf(pv - bf2f(hi));
    }
}

__global__ __launch_bounds__(256) void router_kernel(const float* X, const float* wn, const float* rw,
                                                     float* probs, float* lse, int* cnt, int* ltok, int* lrow) {
    __shared__ float xs[1024];
    __shared__ float red[4];
    __shared__ float lg[8];
    const int t = blockIdx.x;
    const float* r = X + (size_t)t * 1024;
    for (int j = threadIdx.x; j < 1024; j += 256) xs[j] = r[j];
    __syncthreads();
    float ss = 0.f;
    for (int j = threadIdx.x; j < 1024; j += 256) ss += xs[j] * xs[j];
    ss = block_sum256(ss, red);
    const float sc = 32.f / fmaxf(sqrtf(ss), 1e-6f);
    float acc[8] = {0, 0, 0, 0, 0, 0, 0, 0};
    for (int j = threadIdx.x; j < 1024; j += 256) {
        const float xv = xs[j] * wn[j];
#pragma unroll
        for (int e = 0; e < 8; ++e) acc[e] += xv * rw[e * 1024 + j];
    }
#pragma unroll
    for (int e = 0; e < 8; ++e) {
        float s = block_sum256(acc[e], red);
        if (threadIdx.x == 0) lg[e] = s * sc;
    }
    __syncthreads();
    if (threadIdx.x == 0) {
        float m = lg[0];
        for (int e = 1; e < 8; ++e) m = fmaxf(m, lg[e]);
        float ex[8], se = 0.f;
        for (int e = 0; e < 8; ++e) { ex[e] = expf(lg[e] - m); se += ex[e]; }
        const float inv = 1.f / se;
        float pr[8];
        for (int e = 0; e < 8; ++e) { pr[e] = ex[e] * inv; probs[(size_t)t * 8 + e] = pr[e]; }
        lse[t] = m + logf(se);
        int i1 = 0;
        for (int e = 1; e < 8; ++e) if (pr[e] > pr[i1]) i1 = e;
        int i2 = (i1 == 0) ? 1 : 0;
        for (int e = 0; e < 8; ++e) if (e != i1 && pr[e] > pr[i2]) i2 = e;
        int s1 = atomicAdd(&cnt[i1], 1); ltok[i1 * 2048 + s1] = t; lrow[i1 * 2048 + s1] = 2 * t;
        int s2 = atomicAdd(&cnt[i2], 1); ltok[i2 * 2048 + s2] = t; lrow[i2 * 2048 + s2] = 2 * t + 1;
    }
}

__global__ void prefix_kernel(const int* cnt, int* ppd) {
    if (threadIdx.x == 0 && blockIdx.x == 0) {
        int a = 0;
        for (int e = 0; e < 8; ++e) { ppd[e] = a; a += ((cnt[e] + 255) >> 8) << 8; }
    }
}

__global__ __launch_bounds__(256) void gather_kernel(const short* XNH, const short* XNL,
                                                     const int* cnt, const int* ppd, const int* ltok,
                                                     short* GXNH, short* GXNL) {
    const int e = blockIdx.y, i = blockIdx.x;
    if (i >= cnt[e]) return;
    const int t = ltok[e * 2048 + i];
    const int pd = ppd[e] + i;
    const int plane = threadIdx.x >> 7, g = threadIdx.x & 127;
    const long goff = ((long)(g >> 2) << 12) + ((long)(g & 3) << 10);
    const long src = (long)(t >> 7) * 131072 + goff + ((t & 127) << 3);
    const long dst = (long)(pd >> 7) * 131072 + goff + ((pd & 127) << 3);
    const short* S = plane ? XNL : XNH;
    short* D = plane ? GXNL : GXNH;
    *(uint4*)(D + dst) = *(const uint4*)(S + src);
}

// silu over padded U rows [6144][4096] -> tiled split H (K=2048)
__global__ __launch_bounds__(256) void silu_mul(const float* U, short* HH, short* HL) {
    const int row = blockIdx.x, g = threadIdx.x;
    const float* ur = U + (long)row * 4096 + g * 8;
    const float4 u0 = *(const float4*)ur, u1 = *(const float4*)(ur + 4);
    const float4 g0 = *(const float4*)(ur + 2048), g1 = *(const float4*)(ur + 2052);
    float h[8];
    h[0] = (u0.x / (1.f + expf(-u0.x))) * g0.x;
    h[1] = (u0.y / (1.f + expf(-u0.y))) * g0.y;
    h[2] = (u0.z / (1.f + expf(-u0.z))) * g0.z;
    h[3] = (u0.w / (1.f + expf(-u0.w))) * g0.w;
    h[4] = (u1.x / (1.f + expf(-u1.x))) * g1.x;
    h[5] = (u1.y / (1.f + expf(-u1.y))) * g1.y;
    h[6] = (u1.z / (1.f + expf(-u1.z))) * g1.z;
    h[7] = (u1.w / (1.f + expf(-u1.w))) * g1.w;
    const long dst = (long)(row >> 7) * 262144 + ((long)(g >> 2) << 12) + ((long)(g & 3) << 10) + ((row & 127) << 3);
    short hh[8], ll[8];
#pragma unroll
    for (int j = 0; j < 8; ++j) { hh[j] = f2bf(h[j]); ll[j] = f2bf(h[j] - bf2f(hh[j])); }
    *(ushort4*)(HH + dst)     = make_ushort4((unsigned short)hh[0], (unsigned short)hh[1], (unsigned short)hh[2], (unsigned short)hh[3]);
    *(ushort4*)(HH + dst + 4) = make_ushort4((unsigned short)hh[4], (unsigned short)hh[5], (unsigned short)hh[6], (unsigned short)hh[7]);
    *(ushort4*)(HL + dst)     = make_ushort4((unsigned short)ll[0], (unsigned short)ll[1], (unsigned short)ll[2], (unsigned short)ll[3]);
    *(ushort4*)(HL + dst + 4) = make_ushort4((unsigned short)ll[4], (unsigned short)ll[5], (unsigned short)ll[6], (unsigned short)ll[7]);
}

__global__ __launch_bounds__(256) void combine_kernel(float* X, const float* Y) {
    const int i4 = blockIdx.x * 256 + threadIdx.x;
    const int t = i4 >> 8, d4 = i4 & 255;
    float4 x = ((float4*)X)[i4];
    const float4 a = ((const float4*)Y)[(size_t)(2 * t) * 256 + d4];
    const float4 b = ((const float4*)Y)[(size_t)(2 * t + 1) * 256 + d4];
    x.x += a.x + b.x; x.y += a.y + b.y; x.z += a.z + b.z; x.w += a.w + b.w;
    ((float4*)X)[i4] = x;
}

__global__ __launch_bounds__(256) void aux_kernel(const float* probs, const float* lse, float* auxb, int layer) {
    __shared__ float red[4];
    float sl = 0.f;
    for (int t = threadIdx.x; t < 2048; t += 256) sl += lse[t];
    sl = block_sum256(sl, red);
    float s1 = 0.f, s2 = 0.f;
    for (int i = threadIdx.x; i < 8192; i += 256) {
        const float l = probs[i] + probs[8192 + i];
        s1 += l; s2 += l * l;
    }
    s1 = block_sum256(s1, red);
    s2 = block_sum256(s2, red);
    if (threadIdx.x == 0) {
        const float ml = sl / 2048.f;
        const float mean = s1 / 8192.f;
        const float var = fmaxf((s2 - s1 * s1 / 8192.f) / 8191.f, 0.f);
        auxb[layer] = 0.001f * (ml * ml + var / (mean * mean));
    }
}

__global__ void finalize_aux(const float* auxb, float* out) {
    if (threadIdx.x == 0 && blockIdx.x == 0)
        out[(size_t)2 * 1024 * 32000] = auxb[0] + auxb[1];
}

// ---------------- launch helpers ----------------
static void run_gemm128(hipStream_t s, bool split, GemmP& p, int ntiles, int mtiles, int zdim) {
    p.ntiles = ntiles;
    p.G = ntiles * zdim;
    p.Gx = (p.G + 7) >> 3;
    long nb = 8L * p.Gx * mtiles;
    dim3 g((unsigned)nb, 1, 1), b(256);
    if (split) gemm_bt128<true><<<g, b, 65536, s>>>(p);
    else       gemm_bt128<false><<<g, b, 32768, s>>>(p);
}

static void run_gemm256(hipStream_t s, bool split, GemmP& p, int ntiles, int mtiles, int zdim) {
    p.ntiles = ntiles;
    p.G = ntiles * zdim;
    p.Gx = (p.G + 7) >> 3;
    long nb = 8L * p.Gx * mtiles;
    dim3 g((unsigned)nb, 1, 1), b(512);
    if (split) gemm_bt256<true><<<g, b, 98304, s>>>(p);
    else       gemm_bt256<false><<<g, b, 49152, s>>>(p);
}

static void run_tile(hipStream_t s, const float* src, short* hi, short* lo,
                     long rows, int K, long chunkRows, long chunkPanelStride) {
    long groups = rows * (K / 8);
    long nb = (groups + 255) / 256; if (nb > 2048) nb = 2048;
    conv_tile<<<(unsigned)nb, 256, 0, s>>>(src, hi, lo, groups, K / 8, chunkRows, chunkPanelStride);
}

extern "C" void kernel_launch(void* const* d_in, const int* in_sizes, int n_in,
                              void* d_out, int out_size, void* d_ws, size_t ws_size,
                              hipStream_t stream) {
    (void)in_sizes; (void)n_in; (void)out_size; (void)ws_size;
    const int*   tokens = (const int*)d_in[0];
    const float* tok_emb = (const float*)d_in[1];
    const float* norm1 = (const float*)d_in[2];
    const float* norm2 = (const float*)d_in[3];
    const float* wq = (const float*)d_in[4];
    const float* wk = (const float*)d_in[5];
    const float* wv = (const float*)d_in[6];
    const float* wo = (const float*)d_in[7];
    const float* rw = (const float*)d_in[8];
    const float* w1 = (const float*)d_in[9];
    const float* w2 = (const float*)d_in[10];
    const float* w3 = (const float*)d_in[11];
    const float* normf = (const float*)d_in[12];
    const float* headw = (const float*)d_in[13];
    float* out = (float*)d_out;

    char* w = (char*)d_ws;
    const size_t MB = 1024ull * 1024ull;
    float* X    = (float*)(w + 0);            // 8 MB residual fp32
    short* XNH  = (short*)(w + 8 * MB);
    short* XNL  = (short*)(w + 12 * MB);
    short* QRH  = (short*)(w + 16 * MB);      // tiled Q-hat; aliased as AO after QK^T
    short* QRL  = (short*)(w + 20 * MB);
    short* AOH  = QRH;
    short* AOL  = QRL;
    short* KRH  = (short*)(w + 24 * MB);
    short* KRL  = (short*)(w + 25 * MB);
    short* VTH  = (short*)(w + 26 * MB);
    short* VTL  = (short*)(w + 28 * MB);
    // BIG union region 32..216 MB:
    float* QKV  = (float*)(w + 32 * MB);      // 12 MB (attn phase)
    float* SC   = (float*)(w + 32 * MB);      // 128 MB (attn phase)
    short* GXNH = (short*)(w + 32 * MB);      // 12 MB (MoE phase, 6144 rows)
    short* GXNL = (short*)(w + 44 * MB);      // 12 MB
    float* U    = (float*)(w + 56 * MB);      // 96 MB [6144][4096]
    short* HH   = (short*)(w + 152 * MB);     // 24 MB
    short* HL   = (short*)(w + 176 * MB);     // 24 MB
    float* Y    = (float*)(w + 200 * MB);     // 16 MB
    float* PROBS= (float*)(w + 216 * MB);               // 64 KB
    float* LSE  = (float*)(w + 216 * MB + 65536);
    int*   CNT  = (int*)  (w + 216 * MB + 73728);
    int*   PPD  = (int*)  (w + 216 * MB + 73856);
    int*   LTOK = (int*)  (w + 216 * MB + 74240);
    int*   LROW = (int*)  (w + 216 * MB + 74240 + 65536);
    float* AUXB = (float*)(w + 216 * MB + 74240 + 131072);
    // converted weights (all TILED):
    short* WQKVH = (short*)(w + 218 * MB);    // 6 MB
    short* WQKVL = (short*)(w + 224 * MB);    // 6 MB
    short* WOH   = (short*)(w + 230 * MB);    // 4 MB
    short* WOL   = (short*)(w + 234 * MB);    // 4 MB
    short* W12H  = (short*)(w + 238 * MB);    // 64 MB per-layer
    short* W12L  = (short*)(w + 302 * MB);    // 64 MB (layer 0 only; head aliases after)
    short* W3H   = (short*)(w + 366 * MB);    // 32 MB per-layer
    short* W3L   = (short*)(w + 398 * MB);    // 32 MB (layer 0 only)
    short* HDH   = (short*)(w + 302 * MB);    // 62.5 MB, aliases W12L
    // total ~430 MB

    RopeF rf;
    for (int i = 0; i < 32; ++i) {
        float t = (float)pow(10000.0, (double)(2 * i) / 64.0);
        rf.f[i] = 1.0f / t;
    }

    for (int l = 0; l < 2; ++l) {
        long qo = (long)l * 1572864;
        run_tile(stream, wq + (long)l * 1048576, WQKVH + qo,           WQKVL + qo,           1024, 1024, 1024, 8);
        run_tile(stream, wk + (long)l * 262144,  WQKVH + qo + 1048576, WQKVL + qo + 1048576, 256, 1024, 256, 2);
        run_tile(stream, wv + (long)l * 262144,  WQKVH + qo + 1310720, WQKVL + qo + 1310720, 256, 1024, 256, 2);
    }
    run_tile(stream, wo, WOH, WOL, 2048, 1024, 2048, 16);

    embed_kernel<<<2048, 256, 0, stream>>>(tokens, tok_emb, X);

    for (int l = 0; l < 2; ++l) {
        const bool msp = (l == 0);
        run_tile(stream, w1 + (long)l * 16777216, W12H,           msp ? W12L : nullptr,           16384, 1024, 2048, 32);
        run_tile(stream, w2 + (long)l * 16777216, W12H + 2097152, msp ? W12L + 2097152 : nullptr, 16384, 1024, 2048, 32);
        run_tile(stream, w3 + (long)l * 16777216, W3H,            msp ? W3L : nullptr,            8192, 2048, 8192, 64);

        rmsnorm_split<<<2048, 256, 0, stream>>>(X, norm1 + l * 1024, XNH, XNL);

        // fused QKV (bt128 split): [2048][1536] fp32
        { GemmP p = {}; p.Ah = XNH; p.Al = XNL; p.Bh = WQKVH + (long)l * 1572864; p.Bl = WQKVL + (long)l * 1572864;
          p.C = QKV; p.M = 2048; p.N = 1536; p.K = 1024; p.aPanelsZ = 16; p.ldc = 1536; p.alpha = 1.f;
          run_gemm128(stream, true, p, 12, 16, 1); }

        rope_fused_kernel<<<7168, 256, 0, stream>>>(QKV, QRH, QRL, KRH, KRL, VTH, VTL, rf);

        // scores = q k^T / 8 (bt256 split, causal skip nt>2mt+1)
        { GemmP p = {}; p.Ah = QRH; p.Al = QRL; p.Bh = KRH; p.Bl = KRL; p.C = SC;
          p.M = 1024; p.N = 1024; p.K = 64; p.aPanelsZ = 8; p.ldc = 1024;
          p.strideBz = 65536; p.strideCz = 1048576;
          p.alpha = 0.125f; p.gqaB = 1; p.causalSkip = 1;
          run_gemm256(stream, true, p, 8, 4, 32); }

        attn_softmax<<<32768, 256, 0, stream>>>(SC);

        // PV (dedicated kernel, mt-outer decode)
        { GemmP p = {}; p.Ah = (short*)SC; p.Al = (short*)SC + 1024; p.Bh = VTH; p.Bl = VTL; p.Ch = AOH; p.Cl = AOL;
          p.M = 1024; p.N = 64; p.K = 1024; p.lda = 2048;
          p.strideAz = 2097152; p.strideBz = 131072;
          gemm_pv<<<dim3(256), dim3(256), 32768, stream>>>(p); }

        // x += 0.5 * attno @ wo^T (bt128 split)
        { GemmP p = {}; p.Ah = AOH; p.Al = AOL; p.Bh = WOH + (long)l * 1048576; p.Bl = WOL + (long)l * 1048576; p.C = X;
          p.M = 2048; p.N = 1024; p.K = 1024; p.aPanelsZ = 16; p.ldc = 1024;
          p.alpha = 0.5f; p.outMode = 1;
          run_gemm128(stream, true, p, 8, 16, 1); }

        // ---- MoE ----
        rmsnorm_split<<<2048, 256, 0, stream>>>(X, norm2 + l * 1024, XNH, XNL);
        hipMemsetAsync(CNT, 0, 8 * sizeof(int), stream);
        router_kernel<<<2048, 256, 0, stream>>>(X, norm2 + l * 1024, rw + (size_t)l * 8 * 1024,
                                                PROBS, LSE, CNT, LTOK, LROW);
        prefix_kernel<<<1, 64, 0, stream>>>(CNT, PPD);
        { dim3 gg(2048, 8); gather_kernel<<<gg, 256, 0, stream>>>(XNH, XNL, CNT, PPD, LTOK, GXNH, GXNL); }

        // fused u|g
        if (msp) {
            GemmP p = {}; p.Ah = GXNH; p.Al = GXNL; p.Bh = W12H; p.Bl = W12L; p.C = U;
            p.M = 2048; p.N = 4096; p.K = 1024; p.ldc = 4096;
            p.strideBz = 4194304; p.strideCz = 0; p.alpha = 1.f; p.grouped = 1;
            p.cnt = CNT; p.ppd = PPD; p.lrow = LROW;
            run_gemm128(stream, true, p, 32, 16, 8);
        } else {
            GemmP p = {}; p.Ah = GXNH; p.Al = GXNL; p.Bh = W12H; p.Bl = W12L; p.C = U;
            p.M = 2048; p.N = 4096; p.K = 1024; p.ldc = 4096;
            p.strideBz = 4194304; p.strideCz = 0; p.alpha = 1.f; p.grouped = 1;
            p.cnt = CNT; p.ppd = PPD; p.lrow = LROW;
            run_gemm256(stream, false, p, 32, 8, 8);
        }
        silu_mul<<<6144, 256, 0, stream>>>(U, HH, HL);
        // y = h @ w3^T, scatter rows by lrow into Y
        if (msp) {
            GemmP p = {}; p.Ah = HH; p.Al = HL; p.Bh = W3H; p.Bl = W3L; p.C = Y;
            p.M = 2048; p.N = 1024; p.K = 2048; p.ldc = 1024;
            p.strideBz = 2097152; p.strideCz = 0; p.alpha = 1.f; p.grouped = 2;
            p.cnt = CNT; p.ppd = PPD; p.lrow = LROW;
            run_gemm128(stream, true, p, 8, 16, 8);
        } else {
            GemmP p = {}; p.Ah = HH; p.Al = HL; p.Bh = W3H; p.Bl = W3L; p.C = Y;
            p.M = 2048; p.N = 1024; p.K = 2048; p.ldc = 1024;
            p.strideBz = 2097152; p.strideCz = 0; p.alpha = 1.f; p.grouped = 2;
            p.cnt = CNT; p.ppd = PPD; p.lrow = LROW;
            run_gemm256(stream, false, p, 8, 8, 8);
        }
        combine_kernel<<<2048, 256, 0, stream>>>(X, Y);
        aux_kernel<<<1, 256, 0, stream>>>(PROBS, LSE, AUXB, l);

        if (l == 0)
            run_tile(stream, headw, HDH, nullptr, 32000, 1024, 32000, 250);
    }

    rmsnorm_split<<<2048, 256, 0, stream>>>(X, normf, XNH, XNL);
    { GemmP p = {}; p.Ah = XNH; p.Bh = HDH; p.C = out;
      p.M = 2048; p.N = 32000; p.K = 1024; p.aPanelsZ = 16; p.ldc = 32000; p.alpha = 1.f;
      run_gemm256(stream, false, p, 250, 8, 1); }
    finalize_aux<<<1, 1, 0, stream>>>(AUXB, out);
}